// Round 15
// baseline (114.274 us; speedup 1.0000x reference)
//
#include <hip/hip_runtime.h>
#include <hip/hip_bf16.h>
#include <stddef.h>
#include <stdint.h>

#define DM    512
#define NHEAD 8
#define DHEAD 64
#define QLEN  1024
#define KLEN  2048
#define MLEN  1024
#define B_SZ  4

typedef __attribute__((ext_vector_type(8))) short short8;
typedef __attribute__((ext_vector_type(8))) unsigned short ushort8;
typedef __attribute__((ext_vector_type(4))) float floatx4;

static __device__ __forceinline__ unsigned short f2bf(float f) {
  unsigned int u = __float_as_uint(f);
  unsigned int r = (u + 0x7FFFu + ((u >> 16) & 1u)) >> 16;
  return (unsigned short)r;
}
static __device__ __forceinline__ float bf2f(unsigned short h) {
  return __uint_as_float(((unsigned int)h) << 16);
}

template <int CTRL>
static __device__ __forceinline__ float maxdpp(float v) {
  int sh = __builtin_amdgcn_update_dpp(0, __float_as_int(v), CTRL, 0xF, 0xF, true);
  return fmaxf(v, __int_as_float(sh));
}
static __device__ __forceinline__ float rowmax16(float v) {
  v = maxdpp<0xB1>(v);    // quad_perm [1,0,3,2]
  v = maxdpp<0x4E>(v);    // quad_perm [2,3,0,1]
  v = maxdpp<0x124>(v);   // row_ror:4
  v = maxdpp<0x128>(v);   // row_ror:8
  return v;
}

#define GLOAD_LDS16(gsrc, ldst)                                               \
  __builtin_amdgcn_global_load_lds(                                           \
      (const __attribute__((address_space(1))) unsigned int*)(gsrc),          \
      (__attribute__((address_space(3))) unsigned int*)(ldst), 16, 0, 0)

// ---------------------------------------------------------------------------
// Merged prep: x->bf16 | p->bf16 | Wq/k/v/p transpose | Wo hi/lo split.
// ---------------------------------------------------------------------------
__global__ __launch_bounds__(256) void k_prep(
    const float* __restrict__ x, const float* __restrict__ p,
    const float* __restrict__ Wq, const float* __restrict__ Wk,
    const float* __restrict__ Wv, const float* __restrict__ Wp,
    const float* __restrict__ Wo,
    unsigned short* __restrict__ xb, unsigned short* __restrict__ pb,
    unsigned short* __restrict__ wt,
    unsigned short* __restrict__ woh, unsigned short* __restrict__ wol) {
  __shared__ float tile[64][65];
  const int bid = blockIdx.x;
  const int tid = threadIdx.x;
  if (bid < 2048) {
    const int i = bid * 256 + tid;
    float4 a = *(const float4*)(x + (size_t)i * 8);
    float4 b = *(const float4*)(x + (size_t)i * 8 + 4);
    ushort8 o;
    o[0] = f2bf(a.x); o[1] = f2bf(a.y); o[2] = f2bf(a.z); o[3] = f2bf(a.w);
    o[4] = f2bf(b.x); o[5] = f2bf(b.y); o[6] = f2bf(b.z); o[7] = f2bf(b.w);
    *(ushort8*)(xb + (size_t)i * 8) = o;
  } else if (bid < 2560) {
    const int i = (bid - 2048) * 256 + tid;
    float4 a = *(const float4*)(p + (size_t)i * 8);
    float4 b = *(const float4*)(p + (size_t)i * 8 + 4);
    ushort8 o;
    o[0] = f2bf(a.x); o[1] = f2bf(a.y); o[2] = f2bf(a.z); o[3] = f2bf(a.w);
    o[4] = f2bf(b.x); o[5] = f2bf(b.y); o[6] = f2bf(b.z); o[7] = f2bf(b.w);
    *(ushort8*)(pb + (size_t)i * 8) = o;
  } else if (bid < 2816) {
    const int b2 = bid - 2560;
    const int nbq = b2 & 7, kbq = (b2 >> 3) & 7, z = b2 >> 6;
    const float* W = (z == 0) ? Wq : (z == 1) ? Wk : (z == 2) ? Wv : Wp;
    unsigned short* out = wt + (size_t)z * 262144;
    const int row = tid >> 2, c0 = (tid & 3) * 16;
    const int kb = kbq * 64, nb = nbq * 64;
#pragma unroll
    for (int j = 0; j < 4; ++j) {
      float4 ld = *(const float4*)(W + (size_t)(kb + row) * DM + nb + c0 + j * 4);
      tile[row][c0 + j * 4 + 0] = ld.x;
      tile[row][c0 + j * 4 + 1] = ld.y;
      tile[row][c0 + j * 4 + 2] = ld.z;
      tile[row][c0 + j * 4 + 3] = ld.w;
    }
    __syncthreads();
    unsigned short ob[16];
#pragma unroll
    for (int j = 0; j < 16; ++j) ob[j] = f2bf(tile[c0 + j][row]);
    unsigned short* orow = out + (size_t)(nb + row) * DM + kb + c0;
    *(ushort8*)(orow) = *(ushort8*)&ob[0];
    *(ushort8*)(orow + 8) = *(ushort8*)&ob[8];
  } else {
    const int i = (bid - 2816) * 256 + tid;
    ushort8 vh, vl;
#pragma unroll
    for (int j = 0; j < 8; ++j) {
      float f = Wo[(size_t)i * 8 + j];
      unsigned short h = f2bf(f);
      vh[j] = h;
      vl[j] = f2bf(f - bf2f(h));
    }
    *(ushort8*)(woh + (size_t)i * 8) = vh;
    *(ushort8*)(wol + (size_t)i * 8) = vl;
  }
}

// ---------------------------------------------------------------------------
// v_ [B*KLEN][512] bf16 -> vt [b][n][d][KLEN] bf16 (global V transpose)
// ---------------------------------------------------------------------------
__global__ __launch_bounds__(256) void k_vtrans(
    const unsigned short* __restrict__ v_, unsigned short* __restrict__ vt) {
  __shared__ unsigned short tile[64][72];
  const int tid = threadIdx.x;
  const int row = tid >> 2, c0 = (tid & 3) * 16;
  const int kt = blockIdx.x;
  const int bn = blockIdx.y;
  const int bb = bn >> 3, n = bn & 7;
  const unsigned short* src =
      v_ + ((size_t)(bb * KLEN) + kt * 64 + row) * DM + n * DHEAD + c0;
  *(ushort8*)&tile[row][c0] = *(const ushort8*)src;
  *(ushort8*)&tile[row][c0 + 8] = *(const ushort8*)(src + 8);
  __syncthreads();
  unsigned short ob[16];
#pragma unroll
  for (int j = 0; j < 16; ++j) ob[j] = tile[c0 + j][row];
  unsigned short* dst =
      vt + ((size_t)bn * DHEAD + row) * KLEN + kt * 64 + c0;
  *(ushort8*)dst = *(ushort8*)&ob[0];
  *(ushort8*)(dst + 8) = *(ushort8*)&ob[8];
}

// ---------------------------------------------------------------------------
// Fused bf16 MFMA projection GEMM: C[M][512] = A[M][512] * Wt[512][512]^T
// ---------------------------------------------------------------------------
__global__ __launch_bounds__(256) void k_proj_mfma(
    const unsigned short* __restrict__ xb, const unsigned short* __restrict__ pb,
    const unsigned short* __restrict__ wt,
    unsigned short* __restrict__ q_, unsigned short* __restrict__ k_,
    unsigned short* __restrict__ v_, unsigned short* __restrict__ r_) {
  __shared__ unsigned short Abuf[128 * 64];
  __shared__ unsigned short Bbuf[128 * 64];
  const int tid = threadIdx.x, w = tid >> 6, lane = tid & 63;
  const int c = lane & 15, g = lane >> 4;
  const int wr = w >> 1, wc = w & 1;
  const int mb = blockIdx.x, nb = blockIdx.y;
  int prob, mloc;
  const unsigned short* A;
  unsigned short* C;
  if (mb < 32)        { prob = 0; mloc = mb;       A = xb; C = q_; }
  else if (mb < 96)   { prob = 1; mloc = mb - 32;  A = xb; C = k_; }
  else if (mb < 160)  { prob = 2; mloc = mb - 96;  A = xb; C = v_; }
  else                { prob = 3; mloc = mb - 160; A = pb; C = r_; }
  const unsigned short* W = wt + (size_t)prob * 262144;
  const int m0 = mloc * 128;
  const int lrow = lane >> 3, lslot = lane & 7;

  floatx4 acc[4][4];
#pragma unroll
  for (int m = 0; m < 4; ++m)
#pragma unroll
    for (int nn = 0; nn < 4; ++nn) acc[m][nn] = (floatx4){0.f, 0.f, 0.f, 0.f};

  for (int k0 = 0; k0 < DM; k0 += 64) {
    __syncthreads();
#pragma unroll
    for (int iq = 0; iq < 4; ++iq) {
      const int r0 = w * 32 + iq * 8;
      const int arow = r0 + lrow;
      const int mrow = m0 + arow;
      const int grow =
          (prob == 0) ? ((mrow >> 10) * KLEN + (mrow & 1023) + MLEN) : mrow;
      const int sgA = lslot ^ (arow & 7);
      GLOAD_LDS16(A + (size_t)grow * DM + k0 + sgA * 8, Abuf + r0 * 64);
      const int nrow = nb * 128 + arow;
      GLOAD_LDS16(W + (size_t)nrow * DM + k0 + sgA * 8, Bbuf + r0 * 64);
    }
    __syncthreads();
#pragma unroll
    for (int kk = 0; kk < 2; ++kk) {
      short8 af[4], bf[4];
#pragma unroll
      for (int m = 0; m < 4; ++m) {
        const int arow = wr * 64 + m * 16 + c;
        const int slot = (kk * 4 + g) ^ (arow & 7);
        af[m] = *(const short8*)(Abuf + arow * 64 + slot * 8);
      }
#pragma unroll
      for (int nn = 0; nn < 4; ++nn) {
        const int brow = wc * 64 + nn * 16 + c;
        const int slot = (kk * 4 + g) ^ (brow & 7);
        bf[nn] = *(const short8*)(Bbuf + brow * 64 + slot * 8);
      }
#pragma unroll
      for (int m = 0; m < 4; ++m)
#pragma unroll
        for (int nn = 0; nn < 4; ++nn)
          acc[m][nn] = __builtin_amdgcn_mfma_f32_16x16x32_bf16(
              af[m], bf[nn], acc[m][nn], 0, 0, 0);
    }
  }
#pragma unroll
  for (int m = 0; m < 4; ++m)
#pragma unroll
    for (int nn = 0; nn < 4; ++nn)
#pragma unroll
      for (int rg = 0; rg < 4; ++rg) {
        const int row = m0 + wr * 64 + m * 16 + 4 * g + rg;
        const int col = nb * 128 + wc * 64 + nn * 16 + c;
        C[(size_t)row * DM + col] = f2bf(acc[m][nn][rg]);
      }
}

// ---------------------------------------------------------------------------
// out[4096][512] = Ah*Bh^T + Al*Bh^T + Ah*Bl^T  (split-bf16, f32 accum)
// 128M x 64N tiles, grid (32,8); proj-style staging, 48 KB LDS.
// ---------------------------------------------------------------------------
__global__ __launch_bounds__(256) void k_out_mfma(
    const unsigned short* __restrict__ Ah, const unsigned short* __restrict__ Al,
    const unsigned short* __restrict__ Bh, const unsigned short* __restrict__ Bl,
    float* __restrict__ C) {
  __shared__ unsigned short bufAh[128 * 64], bufAl[128 * 64];
  __shared__ unsigned short bufBh[64 * 64], bufBl[64 * 64];
  const int tid = threadIdx.x, w = tid >> 6, lane = tid & 63;
  const int c = lane & 15, g = lane >> 4;
  const int wr = w >> 1, wc = w & 1;
  const int bm = blockIdx.x, bn = blockIdx.y;
  const int lrow = lane >> 3, lslot = lane & 7;
  floatx4 acc[4][2];
#pragma unroll
  for (int mi = 0; mi < 4; ++mi)
#pragma unroll
    for (int ni = 0; ni < 2; ++ni) acc[mi][ni] = (floatx4){0.f, 0.f, 0.f, 0.f};

  for (int k0 = 0; k0 < DM; k0 += 64) {
    __syncthreads();
#pragma unroll
    for (int iq = 0; iq < 4; ++iq) {
      const int r0 = w * 32 + iq * 8;
      const int arow = r0 + lrow;
      const int sg = lslot ^ (arow & 7);
      GLOAD_LDS16(Ah + (size_t)(bm * 128 + arow) * DM + k0 + sg * 8, bufAh + r0 * 64);
      GLOAD_LDS16(Al + (size_t)(bm * 128 + arow) * DM + k0 + sg * 8, bufAl + r0 * 64);
    }
#pragma unroll
    for (int iq = 0; iq < 2; ++iq) {
      const int r0 = w * 16 + iq * 8;
      const int brow = r0 + lrow;
      const int sg = lslot ^ (brow & 7);
      GLOAD_LDS16(Bh + (size_t)(bn * 64 + brow) * DM + k0 + sg * 8, bufBh + r0 * 64);
      GLOAD_LDS16(Bl + (size_t)(bn * 64 + brow) * DM + k0 + sg * 8, bufBl + r0 * 64);
    }
    __syncthreads();
#pragma unroll
    for (int kk = 0; kk < 2; ++kk) {
      short8 ah[4], al[4], bh[2], bl[2];
#pragma unroll
      for (int mi = 0; mi < 4; ++mi) {
        const int row = wr * 64 + mi * 16 + c;
        const int slot = (kk * 4 + g) ^ (row & 7);
        ah[mi] = *(const short8*)(bufAh + row * 64 + slot * 8);
        al[mi] = *(const short8*)(bufAl + row * 64 + slot * 8);
      }
#pragma unroll
      for (int ni = 0; ni < 2; ++ni) {
        const int row = wc * 32 + ni * 16 + c;
        const int slot = (kk * 4 + g) ^ (row & 7);
        bh[ni] = *(const short8*)(bufBh + row * 64 + slot * 8);
        bl[ni] = *(const short8*)(bufBl + row * 64 + slot * 8);
      }
#pragma unroll
      for (int mi = 0; mi < 4; ++mi)
#pragma unroll
        for (int ni = 0; ni < 2; ++ni) {
          acc[mi][ni] = __builtin_amdgcn_mfma_f32_16x16x32_bf16(
              ah[mi], bh[ni], acc[mi][ni], 0, 0, 0);
          acc[mi][ni] = __builtin_amdgcn_mfma_f32_16x16x32_bf16(
              al[mi], bh[ni], acc[mi][ni], 0, 0, 0);
          acc[mi][ni] = __builtin_amdgcn_mfma_f32_16x16x32_bf16(
              ah[mi], bl[ni], acc[mi][ni], 0, 0, 0);
        }
    }
  }
#pragma unroll
  for (int mi = 0; mi < 4; ++mi)
#pragma unroll
    for (int ni = 0; ni < 2; ++ni)
#pragma unroll
      for (int rg = 0; rg < 4; ++rg) {
        const int row = bm * 128 + wr * 64 + mi * 16 + 4 * g + rg;
        const int col = bn * 64 + wc * 32 + ni * 16 + c;
        C[(size_t)row * DM + col] = acc[mi][ni][rg];
      }
}

// ---------------------------------------------------------------------------
// Flash MFMA attention, split-K: 512 thr = 8 waves = 4 q-subs x 2 key-halves.
// KVBLK=32; per-half K/V double-buffers + 128-row R ring; in-LDS merge.
// (R13 version — proven correct at 75 us.)
// ---------------------------------------------------------------------------
__global__ __launch_bounds__(512, 4) void k_attn_mfma(
    const unsigned short* __restrict__ q, const unsigned short* __restrict__ k,
    const unsigned short* __restrict__ vt, const unsigned short* __restrict__ r,
    const float* __restrict__ bk, const float* __restrict__ br,
    unsigned short* __restrict__ aoh, unsigned short* __restrict__ aol) {
  __shared__ alignas(16) char SMEM[75776];
  unsigned short* Kt  = (unsigned short*)SMEM;            // [2h][2buf][32*64]
  unsigned short* VTt = (unsigned short*)(SMEM + 16384);  // [2h][2buf][64*32]
  unsigned short* Rr  = (unsigned short*)(SMEM + 32768);  // [2h][128*64]
  unsigned short* P   = (unsigned short*)(SMEM + 65536);  // [8][16][40]
  float* oC  = (float*)SMEM;                              // merge: [4][16][68]
  float* mlC = (float*)(SMEM + 17408);                    // merge: [4][2][16]

  const int tid = threadIdx.x;
  const int wave = tid >> 6;
  const int h = wave >> 2;         // key half
  const int w = wave & 3;          // q sub-wave
  const int lane = tid & 63;
  const int c = lane & 15;
  const int g = lane >> 4;
  const int n = blockIdx.y;
  const int b = blockIdx.z;
  const int grp = (n + NHEAD * b) >> 4;
  const int i0 = (grp ? (15 - (int)blockIdx.x) : (int)blockIdx.x) * 64;
  const int qb = i0 + w * 16;

  const unsigned short* vtbn = vt + (size_t)(b * NHEAD + n) * DHEAD * KLEN;
  const unsigned short* kbase = k + (size_t)(b * KLEN) * DM + n * DHEAD;
  const unsigned short* rbase_p = r + n * DHEAD;

  const int nkb = i0 / 32 + 34;
  const int nIt = nkb >> 1;
  const int g0r = 960 - i0;

  short8 aqk[2], aqr[2];
  {
    const unsigned short* qrow =
        q + ((size_t)(b * QLEN) + qb + c) * DM + n * DHEAD;
#pragma unroll
    for (int kb2 = 0; kb2 < 2; ++kb2) {
      short8 qv = *(const short8*)(qrow + kb2 * 32 + g * 8);
#pragma unroll
      for (int j = 0; j < 8; ++j) {
        int d = kb2 * 32 + g * 8 + j;
        float f = bf2f((unsigned short)qv[j]);
        aqk[kb2][j] = (short)f2bf((f + bk[n * DHEAD + d]) * 0.125f);
        aqr[kb2][j] = (short)f2bf((f + br[n * DHEAD + d]) * 0.125f);
      }
    }
  }

  floatx4 o[4];
#pragma unroll
  for (int t = 0; t < 4; ++t) o[t] = (floatx4){0.f, 0.f, 0.f, 0.f};
  float m[4], lsum[4], shc[4];
#pragma unroll
  for (int rg = 0; rg < 4; ++rg) { m[rg] = -1e30f; lsum[rg] = 0.f; shc[rg] = 0.f; }

  int bt = 0;

  auto STAGE = [&](int itn) {
    const int buf = itn & 1;
    const int hh = tid >> 8;
    const int idx = tid & 255;
    const int tn = hh * nIt + itn;
    {  // K [32key][64d], 8 slots/row
      const int row = idx >> 3, slot = idx & 7;
      GLOAD_LDS16(kbase + (size_t)(32 * tn + row) * DM + (slot ^ (row & 7)) * 8,
                  Kt + (hh * 2 + buf) * 2048 + idx * 8);
    }
    {  // V^T [64d][32key], 4 slots/row
      const int row = idx >> 2, slot = idx & 3;
      GLOAD_LDS16(vtbn + (size_t)row * KLEN + 32 * tn +
                      ((slot ^ ((row >> 1) & 3)) * 8),
                  VTt + (hh * 2 + buf) * 2048 + idx * 8);
    }
    {  // R: 32 new ring rows
      const int row = idx >> 3, slot = idx & 7;
      const int sb = (bt + 96) & 127;
      const int gst = g0r + hh * (32 * nIt);
      const int grow = min(gst + 32 * itn + 64 + row, KLEN - 1);
      GLOAD_LDS16(rbase_p + (size_t)grow * DM + (slot ^ (row & 7)) * 8,
                  Rr + hh * 8192 + (sb + row) * 64 + slot * 8);
    }
  };

  // prologue
  {
    const int hh = tid >> 8;
    const int idx = tid & 255;
    const int tn = hh * nIt;
    {
      const int row = idx >> 3, slot = idx & 7;
      GLOAD_LDS16(kbase + (size_t)(32 * tn + row) * DM + (slot ^ (row & 7)) * 8,
                  Kt + (hh * 2) * 2048 + idx * 8);
    }
    {
      const int row = idx >> 2, slot = idx & 3;
      GLOAD_LDS16(vtbn + (size_t)row * KLEN + 32 * tn +
                      ((slot ^ ((row >> 1) & 3)) * 8),
                  VTt + (hh * 2) * 2048 + idx * 8);
    }
  }
#pragma unroll
  for (int p = 0; p < 3; ++p) {
    const int Lr = tid + p * 512;
    const int hh = (Lr >= 768) ? 1 : 0;
    const int idx = Lr - hh * 768;
    const int row = idx >> 3, slot = idx & 7;
    const int gst = g0r + hh * (32 * nIt);
    const int grow = min(gst + row, KLEN - 1);
    GLOAD_LDS16(rbase_p + (size_t)grow * DM + (slot ^ (row & 7)) * 8,
                Rr + hh * 8192 + row * 64 + slot * 8);
  }
  __syncthreads();

  const int s0 = (g ^ (c & 7)) * 8;
  const int s1 = ((4 + g) ^ (c & 7)) * 8;
  const int vs0 = (g ^ ((c >> 1) & 3)) * 8;
  unsigned short* Pw = P + (size_t)wave * 640;

  for (int it = 0; it < nIt; ++it) {
    if (it + 1 < nIt) STAGE(it + 1);
    const int t = h * nIt + it;
    const bool act = (32 * t <= qb + 15 + MLEN);
    if (act) {
      const unsigned short* Kc = Kt + (h * 2 + (it & 1)) * 2048;
      const unsigned short* Vc = VTt + (h * 2 + (it & 1)) * 2048;
      const unsigned short* Rh = Rr + h * 8192;

      float sh[3][4];
      if (it == 0) {
        const int rs = ((bt + 16 * (3 - w)) & 127) + c;
        const unsigned short* Rrow = Rh + rs * 64;
        short8 rf0 = *(const short8*)(Rrow + s0);
        short8 rf1 = *(const short8*)(Rrow + s1);
        floatx4 bd = (floatx4){0.f, 0.f, 0.f, 0.f};
        bd = __builtin_amdgcn_mfma_f32_16x16x32_bf16(aqr[0], rf0, bd, 0, 0, 0);
        bd = __builtin_amdgcn_mfma_f32_16x16x32_bf16(aqr[1], rf1, bd, 0, 0, 0);
#pragma unroll
        for (int rg = 0; rg < 4; ++rg) {
          const int srcl = (g << 4) | ((15 + c - 4 * g - rg) & 15);
          sh[0][rg] = __shfl(bd[rg], srcl, 64);
        }
      } else {
#pragma unroll
        for (int rg = 0; rg < 4; ++rg) sh[0][rg] = shc[rg];
      }
#pragma unroll
      for (int t5 = 1; t5 < 3; ++t5) {
        const int rs = ((bt + 16 * (t5 + 3 - w)) & 127) + c;
        const unsigned short* Rrow = Rh + rs * 64;
        short8 rf0 = *(const short8*)(Rrow + s0);
        short8 rf1 = *(const short8*)(Rrow + s1);
        floatx4 bd = (floatx4){0.f, 0.f, 0.f, 0.f};
        bd = __builtin_amdgcn_mfma_f32_16x16x32_bf16(aqr[0], rf0, bd, 0, 0, 0);
        bd = __builtin_amdgcn_mfma_f32_16x16x32_bf16(aqr[1], rf1, bd, 0, 0, 0);
#pragma unroll
        for (int rg = 0; rg < 4; ++rg) {
          const int srcl = (g << 4) | ((15 + c - 4 * g - rg) & 15);
          sh[t5][rg] = __shfl(bd[rg], srcl, 64);
        }
      }
#pragma unroll
      for (int rg = 0; rg < 4; ++rg) shc[rg] = sh[2][rg];

      const int thr = qb + MLEN - 32 * t;
      floatx4 s[2];
      __builtin_amdgcn_s_setprio(1);
#pragma unroll
      for (int tau = 0; tau < 2; ++tau) {
        const int kr = tau * 16 + c;
        short8 kf0 = *(const short8*)(Kc + kr * 64 + s0);
        short8 kf1 = *(const short8*)(Kc + kr * 64 + s1);
        floatx4 acc = (floatx4){0.f, 0.f, 0.f, 0.f};
        acc = __builtin_amdgcn_mfma_f32_16x16x32_bf16(aqk[0], kf0, acc, 0, 0, 0);
        acc = __builtin_amdgcn_mfma_f32_16x16x32_bf16(aqk[1], kf1, acc, 0, 0, 0);
#pragma unroll
        for (int rg = 0; rg < 4; ++rg) {
          const int ql = 4 * g + rg;
          float sv = acc[rg] + ((c > ql) ? sh[tau + 1][rg] : sh[tau][rg]);
          if (tau * 16 + c > thr + ql) sv = -1e30f;
          s[tau][rg] = sv;
        }
      }
      __builtin_amdgcn_s_setprio(0);

      float mx[4];
      bool ok = true;
#pragma unroll
      for (int rg = 0; rg < 4; ++rg) {
        float v2 = rowmax16(fmaxf(s[0][rg], s[1][rg]));
        mx[rg] = v2;
        ok = ok && (v2 <= m[rg] + 8.0f);
      }
      if (!__all(ok)) {
#pragma unroll
        for (int rg = 0; rg < 4; ++rg) {
          float mn = fmaxf(m[rg], mx[rg]);
          float fac = __expf(m[rg] - mn);
          m[rg] = mn;
          lsum[rg] *= fac;
#pragma unroll
          for (int td = 0; td < 4; ++td) o[td][rg] *= fac;
        }
      }
#pragma unroll
      for (int tau = 0; tau < 2; ++tau) {
#pragma unroll
        for (int rg = 0; rg < 4; ++rg) {
          float p = __expf(s[tau][rg] - m[rg]);
          lsum[rg] += p;
          Pw[(4 * g + rg) * 40 + tau * 16 + c] = f2bf(p);
        }
      }

      short8 pa = *(const short8*)(Pw + c * 40 + g * 8);
      __builtin_amdgcn_s_setprio(1);
#pragma unroll
      for (int td = 0; td < 4; ++td) {
        short8 vb = *(const short8*)(Vc + (td * 16 + c) * 32 + vs0);
        o[td] = __builtin_amdgcn_mfma_f32_16x16x32_bf16(pa, vb, o[td], 0, 0, 0);
      }
      __builtin_amdgcn_s_setprio(0);
    }
    __syncthreads();
    bt = (bt + 32) & 127;
  }

#pragma unroll
  for (int rg = 0; rg < 4; ++rg) {
    float L = lsum[rg];
#pragma unroll
    for (int shm = 1; shm < 16; shm <<= 1) L += __shfl_xor(L, shm, 64);
    lsum[rg] = L;
  }

  if (h == 1) {
#pragma unroll
    for (int rg = 0; rg < 4; ++rg) {
      const int ql = 4 * g + rg;
#pragma unroll
      for (int td = 0; td < 4; ++td)
        oC[(w * 16 + ql) * 68 + td * 16 + c] = o[td][rg];
      if (c == 0) {
        mlC[w * 32 + ql] = m[rg];
        mlC[w * 32 + 16 + ql] = lsum[rg];
      }
    }
  }
  __syncthreads();
  if (h == 0) {
#pragma unroll
    for (int rg = 0; rg < 4; ++rg) {
      const int ql = 4 * g + rg;
      const float m1 = mlC[w * 32 + ql];
      const float l1 = mlC[w * 32 + 16 + ql];
      const float M = fmaxf(m[rg], m1);
      const float w0 = __expf(m[rg] - M);
      const float w1 = __expf(m1 - M);
      const float invl = 1.0f / (lsum[rg] * w0 + l1 * w1);
#pragma unroll
      for (int td = 0; td < 4; ++td) {
        float val = (o[td][rg] * w0 + oC[(w * 16 + ql) * 68 + td * 16 + c] * w1) * invl;
        unsigned short hi = f2bf(val);
        float lo = val - bf2f(hi);
        size_t off = ((size_t)(b * QLEN) + qb + ql) * DM + n * DHEAD + td * 16 + c;
        aoh[off] = hi;
        aol[off] = f2bf(lo);
      }
    }
  }
}

// ---------------------------------------------------------------------------
extern "C" void kernel_launch(void* const* d_in, const int* in_sizes, int n_in,
                              void* d_out, int out_size, void* d_ws, size_t ws_size,
                              hipStream_t stream) {
  const float* x  = (const float*)d_in[0];
  const float* p  = (const float*)d_in[1];
  const float* Wq = (const float*)d_in[2];
  const float* Wk = (const float*)d_in[3];
  const float* Wv = (const float*)d_in[4];
  const float* Wo = (const float*)d_in[5];
  const float* Wp = (const float*)d_in[6];
  const float* bk = (const float*)d_in[7];
  const float* br = (const float*)d_in[8];
  float* out = (float*)d_out;

  unsigned short* q_  = (unsigned short*)d_ws;        // 2M u16
  unsigned short* k_  = q_  + (size_t)2097152;        // 4M
  unsigned short* v_  = k_  + (size_t)4194304;        // 4M
  unsigned short* r_  = v_  + (size_t)4194304;        // 1M
  unsigned short* xb  = r_  + (size_t)1048576;        // 4M
  unsigned short* pb  = xb  + (size_t)4194304;        // 1M
  unsigned short* wt  = pb  + (size_t)1048576;        // 1M
  unsigned short* woh = wt  + (size_t)1048576;        // 256K
  unsigned short* wol = woh + (size_t)262144;         // 256K
  unsigned short* aoh = wol + (size_t)262144;         // 2M
  unsigned short* aol = aoh + (size_t)2097152;        // 2M
  unsigned short* vt_ = aol + (size_t)2097152;        // 4M

  k_prep<<<2944, 256, 0, stream>>>(x, p, Wq, Wk, Wv, Wp, Wo,
                                   xb, pb, wt, woh, wol);
  k_proj_mfma<<<dim3(176, 4), 256, 0, stream>>>(xb, pb, wt, q_, k_, v_, r_);
  k_vtrans<<<dim3(KLEN / 64, NHEAD * B_SZ), 256, 0, stream>>>(v_, vt_);
  k_attn_mfma<<<dim3(16, 8, 4), 512, 0, stream>>>(
      q_, k_, vt_, r_, bk, br, aoh, aol);
  k_out_mfma<<<dim3(32, 8), 256, 0, stream>>>(aoh, aol, woh, wol, out);
}

// Round 16
// 108.949 us; speedup vs baseline: 1.0489x; 1.0489x over previous
//
#include <hip/hip_runtime.h>
#include <hip/hip_bf16.h>
#include <stddef.h>
#include <stdint.h>

#define DM    512
#define NHEAD 8
#define DHEAD 64
#define QLEN  1024
#define KLEN  2048
#define MLEN  1024
#define B_SZ  4

typedef __attribute__((ext_vector_type(8))) short short8;
typedef __attribute__((ext_vector_type(8))) unsigned short ushort8;
typedef __attribute__((ext_vector_type(4))) float floatx4;

static __device__ __forceinline__ unsigned short f2bf(float f) {
  unsigned int u = __float_as_uint(f);
  unsigned int r = (u + 0x7FFFu + ((u >> 16) & 1u)) >> 16;
  return (unsigned short)r;
}
static __device__ __forceinline__ float bf2f(unsigned short h) {
  return __uint_as_float(((unsigned int)h) << 16);
}

template <int CTRL>
static __device__ __forceinline__ float maxdpp(float v) {
  int sh = __builtin_amdgcn_update_dpp(0, __float_as_int(v), CTRL, 0xF, 0xF, true);
  return fmaxf(v, __int_as_float(sh));
}
static __device__ __forceinline__ float rowmax16(float v) {
  v = maxdpp<0xB1>(v);    // quad_perm [1,0,3,2]
  v = maxdpp<0x4E>(v);    // quad_perm [2,3,0,1]
  v = maxdpp<0x124>(v);   // row_ror:4
  v = maxdpp<0x128>(v);   // row_ror:8
  return v;
}

#define EXP2F(x) __builtin_amdgcn_exp2f(x)

#define GLOAD_LDS16(gsrc, ldst)                                               \
  __builtin_amdgcn_global_load_lds(                                           \
      (const __attribute__((address_space(1))) unsigned int*)(gsrc),          \
      (__attribute__((address_space(3))) unsigned int*)(ldst), 16, 0, 0)

// ---------------------------------------------------------------------------
// Merged prep: x->bf16 | p->bf16 | Wq/k/v/p transpose | Wo hi/lo split.
// ---------------------------------------------------------------------------
__global__ __launch_bounds__(256) void k_prep(
    const float* __restrict__ x, const float* __restrict__ p,
    const float* __restrict__ Wq, const float* __restrict__ Wk,
    const float* __restrict__ Wv, const float* __restrict__ Wp,
    const float* __restrict__ Wo,
    unsigned short* __restrict__ xb, unsigned short* __restrict__ pb,
    unsigned short* __restrict__ wt,
    unsigned short* __restrict__ woh, unsigned short* __restrict__ wol) {
  __shared__ float tile[64][65];
  const int bid = blockIdx.x;
  const int tid = threadIdx.x;
  if (bid < 2048) {
    const int i = bid * 256 + tid;
    float4 a = *(const float4*)(x + (size_t)i * 8);
    float4 b = *(const float4*)(x + (size_t)i * 8 + 4);
    ushort8 o;
    o[0] = f2bf(a.x); o[1] = f2bf(a.y); o[2] = f2bf(a.z); o[3] = f2bf(a.w);
    o[4] = f2bf(b.x); o[5] = f2bf(b.y); o[6] = f2bf(b.z); o[7] = f2bf(b.w);
    *(ushort8*)(xb + (size_t)i * 8) = o;
  } else if (bid < 2560) {
    const int i = (bid - 2048) * 256 + tid;
    float4 a = *(const float4*)(p + (size_t)i * 8);
    float4 b = *(const float4*)(p + (size_t)i * 8 + 4);
    ushort8 o;
    o[0] = f2bf(a.x); o[1] = f2bf(a.y); o[2] = f2bf(a.z); o[3] = f2bf(a.w);
    o[4] = f2bf(b.x); o[5] = f2bf(b.y); o[6] = f2bf(b.z); o[7] = f2bf(b.w);
    *(ushort8*)(pb + (size_t)i * 8) = o;
  } else if (bid < 2816) {
    const int b2 = bid - 2560;
    const int nbq = b2 & 7, kbq = (b2 >> 3) & 7, z = b2 >> 6;
    const float* W = (z == 0) ? Wq : (z == 1) ? Wk : (z == 2) ? Wv : Wp;
    unsigned short* out = wt + (size_t)z * 262144;
    const int row = tid >> 2, c0 = (tid & 3) * 16;
    const int kb = kbq * 64, nb = nbq * 64;
#pragma unroll
    for (int j = 0; j < 4; ++j) {
      float4 ld = *(const float4*)(W + (size_t)(kb + row) * DM + nb + c0 + j * 4);
      tile[row][c0 + j * 4 + 0] = ld.x;
      tile[row][c0 + j * 4 + 1] = ld.y;
      tile[row][c0 + j * 4 + 2] = ld.z;
      tile[row][c0 + j * 4 + 3] = ld.w;
    }
    __syncthreads();
    unsigned short ob[16];
#pragma unroll
    for (int j = 0; j < 16; ++j) ob[j] = f2bf(tile[c0 + j][row]);
    unsigned short* orow = out + (size_t)(nb + row) * DM + kb + c0;
    *(ushort8*)(orow) = *(ushort8*)&ob[0];
    *(ushort8*)(orow + 8) = *(ushort8*)&ob[8];
  } else {
    const int i = (bid - 2816) * 256 + tid;
    ushort8 vh, vl;
#pragma unroll
    for (int j = 0; j < 8; ++j) {
      float f = Wo[(size_t)i * 8 + j];
      unsigned short h = f2bf(f);
      vh[j] = h;
      vl[j] = f2bf(f - bf2f(h));
    }
    *(ushort8*)(woh + (size_t)i * 8) = vh;
    *(ushort8*)(wol + (size_t)i * 8) = vl;
  }
}

// ---------------------------------------------------------------------------
// v_ [B*KLEN][512] bf16 -> vt [b][n][d][KLEN] bf16 (global V transpose)
// ---------------------------------------------------------------------------
__global__ __launch_bounds__(256) void k_vtrans(
    const unsigned short* __restrict__ v_, unsigned short* __restrict__ vt) {
  __shared__ unsigned short tile[64][72];
  const int tid = threadIdx.x;
  const int row = tid >> 2, c0 = (tid & 3) * 16;
  const int kt = blockIdx.x;
  const int bn = blockIdx.y;
  const int bb = bn >> 3, n = bn & 7;
  const unsigned short* src =
      v_ + ((size_t)(bb * KLEN) + kt * 64 + row) * DM + n * DHEAD + c0;
  *(ushort8*)&tile[row][c0] = *(const ushort8*)src;
  *(ushort8*)&tile[row][c0 + 8] = *(const ushort8*)(src + 8);
  __syncthreads();
  unsigned short ob[16];
#pragma unroll
  for (int j = 0; j < 16; ++j) ob[j] = tile[c0 + j][row];
  unsigned short* dst =
      vt + ((size_t)bn * DHEAD + row) * KLEN + kt * 64 + c0;
  *(ushort8*)dst = *(ushort8*)&ob[0];
  *(ushort8*)(dst + 8) = *(ushort8*)&ob[8];
}

// ---------------------------------------------------------------------------
// Fused bf16 MFMA projection GEMM: C[M][512] = A[M][512] * Wt[512][512]^T
// ---------------------------------------------------------------------------
__global__ __launch_bounds__(256) void k_proj_mfma(
    const unsigned short* __restrict__ xb, const unsigned short* __restrict__ pb,
    const unsigned short* __restrict__ wt,
    unsigned short* __restrict__ q_, unsigned short* __restrict__ k_,
    unsigned short* __restrict__ v_, unsigned short* __restrict__ r_) {
  __shared__ unsigned short Abuf[128 * 64];
  __shared__ unsigned short Bbuf[128 * 64];
  const int tid = threadIdx.x, w = tid >> 6, lane = tid & 63;
  const int c = lane & 15, g = lane >> 4;
  const int wr = w >> 1, wc = w & 1;
  const int mb = blockIdx.x, nb = blockIdx.y;
  int prob, mloc;
  const unsigned short* A;
  unsigned short* C;
  if (mb < 32)        { prob = 0; mloc = mb;       A = xb; C = q_; }
  else if (mb < 96)   { prob = 1; mloc = mb - 32;  A = xb; C = k_; }
  else if (mb < 160)  { prob = 2; mloc = mb - 96;  A = xb; C = v_; }
  else                { prob = 3; mloc = mb - 160; A = pb; C = r_; }
  const unsigned short* W = wt + (size_t)prob * 262144;
  const int m0 = mloc * 128;
  const int lrow = lane >> 3, lslot = lane & 7;

  floatx4 acc[4][4];
#pragma unroll
  for (int m = 0; m < 4; ++m)
#pragma unroll
    for (int nn = 0; nn < 4; ++nn) acc[m][nn] = (floatx4){0.f, 0.f, 0.f, 0.f};

  for (int k0 = 0; k0 < DM; k0 += 64) {
    __syncthreads();
#pragma unroll
    for (int iq = 0; iq < 4; ++iq) {
      const int r0 = w * 32 + iq * 8;
      const int arow = r0 + lrow;
      const int mrow = m0 + arow;
      const int grow =
          (prob == 0) ? ((mrow >> 10) * KLEN + (mrow & 1023) + MLEN) : mrow;
      const int sgA = lslot ^ (arow & 7);
      GLOAD_LDS16(A + (size_t)grow * DM + k0 + sgA * 8, Abuf + r0 * 64);
      const int nrow = nb * 128 + arow;
      GLOAD_LDS16(W + (size_t)nrow * DM + k0 + sgA * 8, Bbuf + r0 * 64);
    }
    __syncthreads();
#pragma unroll
    for (int kk = 0; kk < 2; ++kk) {
      short8 af[4], bf[4];
#pragma unroll
      for (int m = 0; m < 4; ++m) {
        const int arow = wr * 64 + m * 16 + c;
        const int slot = (kk * 4 + g) ^ (arow & 7);
        af[m] = *(const short8*)(Abuf + arow * 64 + slot * 8);
      }
#pragma unroll
      for (int nn = 0; nn < 4; ++nn) {
        const int brow = wc * 64 + nn * 16 + c;
        const int slot = (kk * 4 + g) ^ (brow & 7);
        bf[nn] = *(const short8*)(Bbuf + brow * 64 + slot * 8);
      }
#pragma unroll
      for (int m = 0; m < 4; ++m)
#pragma unroll
        for (int nn = 0; nn < 4; ++nn)
          acc[m][nn] = __builtin_amdgcn_mfma_f32_16x16x32_bf16(
              af[m], bf[nn], acc[m][nn], 0, 0, 0);
    }
  }
#pragma unroll
  for (int m = 0; m < 4; ++m)
#pragma unroll
    for (int nn = 0; nn < 4; ++nn)
#pragma unroll
      for (int rg = 0; rg < 4; ++rg) {
        const int row = m0 + wr * 64 + m * 16 + 4 * g + rg;
        const int col = nb * 128 + wc * 64 + nn * 16 + c;
        C[(size_t)row * DM + col] = f2bf(acc[m][nn][rg]);
      }
}

// ---------------------------------------------------------------------------
// out[4096][512] = Ah*Bh^T + Al*Bh^T + Ah*Bl^T   (split-bf16, f32 accum)
// 64x64 tiles (R13 config — measured best).
// ---------------------------------------------------------------------------
__global__ __launch_bounds__(256) void k_out_mfma(
    const unsigned short* __restrict__ Ah, const unsigned short* __restrict__ Al,
    const unsigned short* __restrict__ Bh, const unsigned short* __restrict__ Bl,
    float* __restrict__ C) {
  __shared__ unsigned short bufAh[64 * 64], bufAl[64 * 64];
  __shared__ unsigned short bufBh[64 * 64], bufBl[64 * 64];
  const int tid = threadIdx.x, w = tid >> 6, lane = tid & 63;
  const int c = lane & 15, g = lane >> 4;
  const int wr = w >> 1, wc = w & 1;
  const int bm = blockIdx.x, bn = blockIdx.y;
  const int lrow = lane >> 3, lslot = lane & 7;
  floatx4 acc[2][2];
#pragma unroll
  for (int mi = 0; mi < 2; ++mi)
#pragma unroll
    for (int ni = 0; ni < 2; ++ni) acc[mi][ni] = (floatx4){0.f, 0.f, 0.f, 0.f};

  for (int k0 = 0; k0 < DM; k0 += 64) {
    __syncthreads();
#pragma unroll
    for (int iq = 0; iq < 2; ++iq) {
      const int r0 = w * 16 + iq * 8;
      const int arow = r0 + lrow;
      const int sg = lslot ^ (arow & 7);
      GLOAD_LDS16(Ah + (size_t)(bm * 64 + arow) * DM + k0 + sg * 8, bufAh + r0 * 64);
      GLOAD_LDS16(Al + (size_t)(bm * 64 + arow) * DM + k0 + sg * 8, bufAl + r0 * 64);
      GLOAD_LDS16(Bh + (size_t)(bn * 64 + arow) * DM + k0 + sg * 8, bufBh + r0 * 64);
      GLOAD_LDS16(Bl + (size_t)(bn * 64 + arow) * DM + k0 + sg * 8, bufBl + r0 * 64);
    }
    __syncthreads();
#pragma unroll
    for (int kk = 0; kk < 2; ++kk) {
      short8 ah[2], al[2], bh[2], bl[2];
#pragma unroll
      for (int mi = 0; mi < 2; ++mi) {
        const int row = wr * 32 + mi * 16 + c;
        const int slot = (kk * 4 + g) ^ (row & 7);
        ah[mi] = *(const short8*)(bufAh + row * 64 + slot * 8);
        al[mi] = *(const short8*)(bufAl + row * 64 + slot * 8);
      }
#pragma unroll
      for (int ni = 0; ni < 2; ++ni) {
        const int row = wc * 32 + ni * 16 + c;
        const int slot = (kk * 4 + g) ^ (row & 7);
        bh[ni] = *(const short8*)(bufBh + row * 64 + slot * 8);
        bl[ni] = *(const short8*)(bufBl + row * 64 + slot * 8);
      }
#pragma unroll
      for (int mi = 0; mi < 2; ++mi)
#pragma unroll
        for (int ni = 0; ni < 2; ++ni) {
          acc[mi][ni] = __builtin_amdgcn_mfma_f32_16x16x32_bf16(
              ah[mi], bh[ni], acc[mi][ni], 0, 0, 0);
          acc[mi][ni] = __builtin_amdgcn_mfma_f32_16x16x32_bf16(
              al[mi], bh[ni], acc[mi][ni], 0, 0, 0);
          acc[mi][ni] = __builtin_amdgcn_mfma_f32_16x16x32_bf16(
              ah[mi], bl[ni], acc[mi][ni], 0, 0, 0);
        }
    }
  }
#pragma unroll
  for (int mi = 0; mi < 2; ++mi)
#pragma unroll
    for (int ni = 0; ni < 2; ++ni)
#pragma unroll
      for (int rg = 0; rg < 4; ++rg) {
        const int row = bm * 64 + wr * 32 + mi * 16 + 4 * g + rg;
        const int col = bn * 64 + wc * 32 + ni * 16 + c;
        C[(size_t)row * DM + col] = acc[mi][ni][rg];
      }
}

// ---------------------------------------------------------------------------
// Flash MFMA attention, split-K: 512 thr = 8 waves = 4 q-subs x 2 key-halves.
// KVBLK=32; per-half K/V double-buffers + 128-row R ring; in-LDS merge.
// Softmax in exp2 domain (log2e folded into Q scale); masked tail peeled.
// ---------------------------------------------------------------------------
__global__ __launch_bounds__(512, 4) void k_attn_mfma(
    const unsigned short* __restrict__ q, const unsigned short* __restrict__ k,
    const unsigned short* __restrict__ vt, const unsigned short* __restrict__ r,
    const float* __restrict__ bk, const float* __restrict__ br,
    unsigned short* __restrict__ aoh, unsigned short* __restrict__ aol) {
  __shared__ alignas(16) char SMEM[75776];
  unsigned short* Kt  = (unsigned short*)SMEM;            // [2h][2buf][32*64]
  unsigned short* VTt = (unsigned short*)(SMEM + 16384);  // [2h][2buf][64*32]
  unsigned short* Rr  = (unsigned short*)(SMEM + 32768);  // [2h][128*64]
  unsigned short* P   = (unsigned short*)(SMEM + 65536);  // [8][16][40]
  float* oC  = (float*)SMEM;                              // merge: [4][16][68]
  float* mlC = (float*)(SMEM + 17408);                    // merge: [4][2][16]

  const int tid = threadIdx.x;
  const int wave = tid >> 6;
  const int h = wave >> 2;         // key half
  const int w = wave & 3;          // q sub-wave
  const int lane = tid & 63;
  const int c = lane & 15;
  const int g = lane >> 4;
  const int n = blockIdx.y;
  const int b = blockIdx.z;
  const int grp = (n + NHEAD * b) >> 4;
  const int i0 = (grp ? (15 - (int)blockIdx.x) : (int)blockIdx.x) * 64;
  const int qb = i0 + w * 16;

  const unsigned short* vtbn = vt + (size_t)(b * NHEAD + n) * DHEAD * KLEN;
  const unsigned short* kbase = k + (size_t)(b * KLEN) * DM + n * DHEAD;
  const unsigned short* rbase_p = r + n * DHEAD;

  const int nkb = i0 / 32 + 34;
  const int nIt = nkb >> 1;
  const int g0r = 960 - i0;

  // Q fragments; scale = (1/8) * log2(e) -> softmax in exp2 domain
  const float QSC = 0.18033688011112042f;
  short8 aqk[2], aqr[2];
  {
    const unsigned short* qrow =
        q + ((size_t)(b * QLEN) + qb + c) * DM + n * DHEAD;
#pragma unroll
    for (int kb2 = 0; kb2 < 2; ++kb2) {
      short8 qv = *(const short8*)(qrow + kb2 * 32 + g * 8);
#pragma unroll
      for (int j = 0; j < 8; ++j) {
        int d = kb2 * 32 + g * 8 + j;
        float f = bf2f((unsigned short)qv[j]);
        aqk[kb2][j] = (short)f2bf((f + bk[n * DHEAD + d]) * QSC);
        aqr[kb2][j] = (short)f2bf((f + br[n * DHEAD + d]) * QSC);
      }
    }
  }

  floatx4 o[4];
#pragma unroll
  for (int t = 0; t < 4; ++t) o[t] = (floatx4){0.f, 0.f, 0.f, 0.f};
  float m[4], lsum[4], shc[4];
#pragma unroll
  for (int rg = 0; rg < 4; ++rg) { m[rg] = -1e30f; lsum[rg] = 0.f; shc[rg] = 0.f; }

  int bt = 0;

  auto STAGE = [&](int itn) {
    const int buf = itn & 1;
    const int hh = tid >> 8;
    const int idx = tid & 255;
    const int tn = hh * nIt + itn;
    {  // K [32key][64d], 8 slots/row
      const int row = idx >> 3, slot = idx & 7;
      GLOAD_LDS16(kbase + (size_t)(32 * tn + row) * DM + (slot ^ (row & 7)) * 8,
                  Kt + (hh * 2 + buf) * 2048 + idx * 8);
    }
    {  // V^T [64d][32key], 4 slots/row
      const int row = idx >> 2, slot = idx & 3;
      GLOAD_LDS16(vtbn + (size_t)row * KLEN + 32 * tn +
                      ((slot ^ ((row >> 1) & 3)) * 8),
                  VTt + (hh * 2 + buf) * 2048 + idx * 8);
    }
    {  // R: 32 new ring rows
      const int row = idx >> 3, slot = idx & 7;
      const int sb = (bt + 96) & 127;
      const int gst = g0r + hh * (32 * nIt);
      const int grow = min(gst + 32 * itn + 64 + row, KLEN - 1);
      GLOAD_LDS16(rbase_p + (size_t)grow * DM + (slot ^ (row & 7)) * 8,
                  Rr + hh * 8192 + (sb + row) * 64 + slot * 8);
    }
  };

  // prologue
  {
    const int hh = tid >> 8;
    const int idx = tid & 255;
    const int tn = hh * nIt;
    {
      const int row = idx >> 3, slot = idx & 7;
      GLOAD_LDS16(kbase + (size_t)(32 * tn + row) * DM + (slot ^ (row & 7)) * 8,
                  Kt + (hh * 2) * 2048 + idx * 8);
    }
    {
      const int row = idx >> 2, slot = idx & 3;
      GLOAD_LDS16(vtbn + (size_t)row * KLEN + 32 * tn +
                      ((slot ^ ((row >> 1) & 3)) * 8),
                  VTt + (hh * 2) * 2048 + idx * 8);
    }
  }
#pragma unroll
  for (int p = 0; p < 3; ++p) {
    const int Lr = tid + p * 512;
    const int hh = (Lr >= 768) ? 1 : 0;
    const int idx = Lr - hh * 768;
    const int row = idx >> 3, slot = idx & 7;
    const int gst = g0r + hh * (32 * nIt);
    const int grow = min(gst + row, KLEN - 1);
    GLOAD_LDS16(rbase_p + (size_t)grow * DM + (slot ^ (row & 7)) * 8,
                Rr + hh * 8192 + row * 64 + slot * 8);
  }
  __syncthreads();

  const int s0 = (g ^ (c & 7)) * 8;
  const int s1 = ((4 + g) ^ (c & 7)) * 8;
  const int vs0 = (g ^ ((c >> 1) & 3)) * 8;
  unsigned short* Pw = P + (size_t)wave * 640;

  for (int it = 0; it < nIt; ++it) {
    if (it + 1 < nIt) STAGE(it + 1);
    const int t = h * nIt + it;
    const bool act = (32 * t <= qb + 15 + MLEN);
    if (act) {
      const unsigned short* Kc = Kt + (h * 2 + (it & 1)) * 2048;
      const unsigned short* Vc = VTt + (h * 2 + (it & 1)) * 2048;
      const unsigned short* Rh = Rr + h * 8192;

      float sh[3][4];
      if (it == 0) {
        const int rs = ((bt + 16 * (3 - w)) & 127) + c;
        const unsigned short* Rrow = Rh + rs * 64;
        short8 rf0 = *(const short8*)(Rrow + s0);
        short8 rf1 = *(const short8*)(Rrow + s1);
        floatx4 bd = (floatx4){0.f, 0.f, 0.f, 0.f};
        bd = __builtin_amdgcn_mfma_f32_16x16x32_bf16(aqr[0], rf0, bd, 0, 0, 0);
        bd = __builtin_amdgcn_mfma_f32_16x16x32_bf16(aqr[1], rf1, bd, 0, 0, 0);
#pragma unroll
        for (int rg = 0; rg < 4; ++rg) {
          const int srcl = (g << 4) | ((15 + c - 4 * g - rg) & 15);
          sh[0][rg] = __shfl(bd[rg], srcl, 64);
        }
      } else {
#pragma unroll
        for (int rg = 0; rg < 4; ++rg) sh[0][rg] = shc[rg];
      }
#pragma unroll
      for (int t5 = 1; t5 < 3; ++t5) {
        const int rs = ((bt + 16 * (t5 + 3 - w)) & 127) + c;
        const unsigned short* Rrow = Rh + rs * 64;
        short8 rf0 = *(const short8*)(Rrow + s0);
        short8 rf1 = *(const short8*)(Rrow + s1);
        floatx4 bd = (floatx4){0.f, 0.f, 0.f, 0.f};
        bd = __builtin_amdgcn_mfma_f32_16x16x32_bf16(aqr[0], rf0, bd, 0, 0, 0);
        bd = __builtin_amdgcn_mfma_f32_16x16x32_bf16(aqr[1], rf1, bd, 0, 0, 0);
#pragma unroll
        for (int rg = 0; rg < 4; ++rg) {
          const int srcl = (g << 4) | ((15 + c - 4 * g - rg) & 15);
          sh[t5][rg] = __shfl(bd[rg], srcl, 64);
        }
      }
#pragma unroll
      for (int rg = 0; rg < 4; ++rg) shc[rg] = sh[2][rg];

      const int thr = qb + MLEN - 32 * t;
      floatx4 s[2];
      __builtin_amdgcn_s_setprio(1);
      if (thr >= 31) {
        // fully unmasked tile (vast majority of iterations)
#pragma unroll
        for (int tau = 0; tau < 2; ++tau) {
          const int kr = tau * 16 + c;
          short8 kf0 = *(const short8*)(Kc + kr * 64 + s0);
          short8 kf1 = *(const short8*)(Kc + kr * 64 + s1);
          floatx4 acc = (floatx4){0.f, 0.f, 0.f, 0.f};
          acc = __builtin_amdgcn_mfma_f32_16x16x32_bf16(aqk[0], kf0, acc, 0, 0, 0);
          acc = __builtin_amdgcn_mfma_f32_16x16x32_bf16(aqk[1], kf1, acc, 0, 0, 0);
#pragma unroll
          for (int rg = 0; rg < 4; ++rg) {
            const int ql = 4 * g + rg;
            s[tau][rg] = acc[rg] + ((c > ql) ? sh[tau + 1][rg] : sh[tau][rg]);
          }
        }
      } else {
#pragma unroll
        for (int tau = 0; tau < 2; ++tau) {
          const int kr = tau * 16 + c;
          short8 kf0 = *(const short8*)(Kc + kr * 64 + s0);
          short8 kf1 = *(const short8*)(Kc + kr * 64 + s1);
          floatx4 acc = (floatx4){0.f, 0.f, 0.f, 0.f};
          acc = __builtin_amdgcn_mfma_f32_16x16x32_bf16(aqk[0], kf0, acc, 0, 0, 0);
          acc = __builtin_amdgcn_mfma_f32_16x16x32_bf16(aqk[1], kf1, acc, 0, 0, 0);
#pragma unroll
          for (int rg = 0; rg < 4; ++rg) {
            const int ql = 4 * g + rg;
            float sv = acc[rg] + ((c > ql) ? sh[tau + 1][rg] : sh[tau][rg]);
            if (tau * 16 + c > thr + ql) sv = -1e30f;
            s[tau][rg] = sv;
          }
        }
      }
      __builtin_amdgcn_s_setprio(0);

      // online softmax (exp2 domain): DPP row-max, defer-max, partial sums
      float mx[4];
      bool ok = true;
#pragma unroll
      for (int rg = 0; rg < 4; ++rg) {
        float v2 = rowmax16(fmaxf(s[0][rg], s[1][rg]));
        mx[rg] = v2;
        ok = ok && (v2 <= m[rg] + 11.54f);
      }
      if (!__all(ok)) {
#pragma unroll
        for (int rg = 0; rg < 4; ++rg) {
          float mn = fmaxf(m[rg], mx[rg]);
          float fac = EXP2F(m[rg] - mn);
          m[rg] = mn;
          lsum[rg] *= fac;
#pragma unroll
          for (int td = 0; td < 4; ++td) o[td][rg] *= fac;
        }
      }
#pragma unroll
      for (int tau = 0; tau < 2; ++tau) {
#pragma unroll
        for (int rg = 0; rg < 4; ++rg) {
          float p = EXP2F(s[tau][rg] - m[rg]);
          lsum[rg] += p;
          Pw[(4 * g + rg) * 40 + tau * 16 + c] = f2bf(p);
        }
      }

      short8 pa = *(const short8*)(Pw + c * 40 + g * 8);
      __builtin_amdgcn_s_setprio(1);
#pragma unroll
      for (int td = 0; td < 4; ++td) {
        short8 vb = *(const short8*)(Vc + (td * 16 + c) * 32 + vs0);
        o[td] = __builtin_amdgcn_mfma_f32_16x16x32_bf16(pa, vb, o[td], 0, 0, 0);
      }
      __builtin_amdgcn_s_setprio(0);
    }
    __syncthreads();
    bt = (bt + 32) & 127;
  }

#pragma unroll
  for (int rg = 0; rg < 4; ++rg) {
    float L = lsum[rg];
#pragma unroll
    for (int shm = 1; shm < 16; shm <<= 1) L += __shfl_xor(L, shm, 64);
    lsum[rg] = L;
  }

  if (h == 1) {
#pragma unroll
    for (int rg = 0; rg < 4; ++rg) {
      const int ql = 4 * g + rg;
#pragma unroll
      for (int td = 0; td < 4; ++td)
        oC[(w * 16 + ql) * 68 + td * 16 + c] = o[td][rg];
      if (c == 0) {
        mlC[w * 32 + ql] = m[rg];
        mlC[w * 32 + 16 + ql] = lsum[rg];
      }
    }
  }
  __syncthreads();
  if (h == 0) {
#pragma unroll
    for (int rg = 0; rg < 4; ++rg) {
      const int ql = 4 * g + rg;
      const float m1 = mlC[w * 32 + ql];
      const float l1 = mlC[w * 32 + 16 + ql];
      const float M = fmaxf(m[rg], m1);
      const float w0 = EXP2F(m[rg] - M);
      const float w1 = EXP2F(m1 - M);
      const float invl = 1.0f / (lsum[rg] * w0 + l1 * w1);
#pragma unroll
      for (int td = 0; td < 4; ++td) {
        float val = (o[td][rg] * w0 + oC[(w * 16 + ql) * 68 + td * 16 + c] * w1) * invl;
        unsigned short hi = f2bf(val);
        float lo = val - bf2f(hi);
        size_t off = ((size_t)(b * QLEN) + qb + ql) * DM + n * DHEAD + td * 16 + c;
        aoh[off] = hi;
        aol[off] = f2bf(lo);
      }
    }
  }
}

// ---------------------------------------------------------------------------
extern "C" void kernel_launch(void* const* d_in, const int* in_sizes, int n_in,
                              void* d_out, int out_size, void* d_ws, size_t ws_size,
                              hipStream_t stream) {
  const float* x  = (const float*)d_in[0];
  const float* p  = (const float*)d_in[1];
  const float* Wq = (const float*)d_in[2];
  const float* Wk = (const float*)d_in[3];
  const float* Wv = (const float*)d_in[4];
  const float* Wo = (const float*)d_in[5];
  const float* Wp = (const float*)d_in[6];
  const float* bk = (const float*)d_in[7];
  const float* br = (const float*)d_in[8];
  float* out = (float*)d_out;

  unsigned short* q_  = (unsigned short*)d_ws;        // 2M u16
  unsigned short* k_  = q_  + (size_t)2097152;        // 4M
  unsigned short* v_  = k_  + (size_t)4194304;        // 4M
  unsigned short* r_  = v_  + (size_t)4194304;        // 1M
  unsigned short* xb  = r_  + (size_t)1048576;        // 4M
  unsigned short* pb  = xb  + (size_t)4194304;        // 1M
  unsigned short* wt  = pb  + (size_t)1048576;        // 1M
  unsigned short* woh = wt  + (size_t)1048576;        // 256K
  unsigned short* wol = woh + (size_t)262144;         // 256K
  unsigned short* aoh = wol + (size_t)262144;         // 2M
  unsigned short* aol = aoh + (size_t)2097152;        // 2M
  unsigned short* vt_ = aol + (size_t)2097152;        // 4M

  k_prep<<<2944, 256, 0, stream>>>(x, p, Wq, Wk, Wv, Wp, Wo,
                                   xb, pb, wt, woh, wol);
  k_proj_mfma<<<dim3(176, 4), 256, 0, stream>>>(xb, pb, wt, q_, k_, v_, r_);
  k_vtrans<<<dim3(KLEN / 64, NHEAD * B_SZ), 256, 0, stream>>>(v_, vt_);
  k_attn_mfma<<<dim3(16, 8, 4), 512, 0, stream>>>(
      q_, k_, vt_, r_, bk, br, aoh, aol);
  k_out_mfma<<<dim3(64, 8), 256, 0, stream>>>(aoh, aol, woh, wol, out);
}

// Round 17
// 101.180 us; speedup vs baseline: 1.1294x; 1.0768x over previous
//
#include <hip/hip_runtime.h>
#include <hip/hip_bf16.h>
#include <stddef.h>
#include <stdint.h>

#define DM    512
#define NHEAD 8
#define DHEAD 64
#define QLEN  1024
#define KLEN  2048
#define MLEN  1024
#define B_SZ  4

typedef __attribute__((ext_vector_type(8))) short short8;
typedef __attribute__((ext_vector_type(8))) unsigned short ushort8;
typedef __attribute__((ext_vector_type(4))) float floatx4;

static __device__ __forceinline__ unsigned short f2bf(float f) {
  unsigned int u = __float_as_uint(f);
  unsigned int r = (u + 0x7FFFu + ((u >> 16) & 1u)) >> 16;
  return (unsigned short)r;
}
static __device__ __forceinline__ float bf2f(unsigned short h) {
  return __uint_as_float(((unsigned int)h) << 16);
}

template <int CTRL>
static __device__ __forceinline__ float maxdpp(float v) {
  int sh = __builtin_amdgcn_update_dpp(0, __float_as_int(v), CTRL, 0xF, 0xF, true);
  return fmaxf(v, __int_as_float(sh));
}
static __device__ __forceinline__ float rowmax16(float v) {
  v = maxdpp<0xB1>(v);    // quad_perm [1,0,3,2]
  v = maxdpp<0x4E>(v);    // quad_perm [2,3,0,1]
  v = maxdpp<0x124>(v);   // row_ror:4
  v = maxdpp<0x128>(v);   // row_ror:8
  return v;
}

#define EXP2F(x) __builtin_amdgcn_exp2f(x)

#define GLOAD_LDS16(gsrc, ldst)                                               \
  __builtin_amdgcn_global_load_lds(                                           \
      (const __attribute__((address_space(1))) unsigned int*)(gsrc),          \
      (__attribute__((address_space(3))) unsigned int*)(ldst), 16, 0, 0)

// ---------------------------------------------------------------------------
// Merged prep: x->bf16 | p->bf16 | Wq/k/v/p transpose | Wo hi/lo split.
// ---------------------------------------------------------------------------
__global__ __launch_bounds__(256) void k_prep(
    const float* __restrict__ x, const float* __restrict__ p,
    const float* __restrict__ Wq, const float* __restrict__ Wk,
    const float* __restrict__ Wv, const float* __restrict__ Wp,
    const float* __restrict__ Wo,
    unsigned short* __restrict__ xb, unsigned short* __restrict__ pb,
    unsigned short* __restrict__ wt,
    unsigned short* __restrict__ woh, unsigned short* __restrict__ wol) {
  __shared__ float tile[64][65];
  const int bid = blockIdx.x;
  const int tid = threadIdx.x;
  if (bid < 2048) {
    const int i = bid * 256 + tid;
    float4 a = *(const float4*)(x + (size_t)i * 8);
    float4 b = *(const float4*)(x + (size_t)i * 8 + 4);
    ushort8 o;
    o[0] = f2bf(a.x); o[1] = f2bf(a.y); o[2] = f2bf(a.z); o[3] = f2bf(a.w);
    o[4] = f2bf(b.x); o[5] = f2bf(b.y); o[6] = f2bf(b.z); o[7] = f2bf(b.w);
    *(ushort8*)(xb + (size_t)i * 8) = o;
  } else if (bid < 2560) {
    const int i = (bid - 2048) * 256 + tid;
    float4 a = *(const float4*)(p + (size_t)i * 8);
    float4 b = *(const float4*)(p + (size_t)i * 8 + 4);
    ushort8 o;
    o[0] = f2bf(a.x); o[1] = f2bf(a.y); o[2] = f2bf(a.z); o[3] = f2bf(a.w);
    o[4] = f2bf(b.x); o[5] = f2bf(b.y); o[6] = f2bf(b.z); o[7] = f2bf(b.w);
    *(ushort8*)(pb + (size_t)i * 8) = o;
  } else if (bid < 2816) {
    const int b2 = bid - 2560;
    const int nbq = b2 & 7, kbq = (b2 >> 3) & 7, z = b2 >> 6;
    const float* W = (z == 0) ? Wq : (z == 1) ? Wk : (z == 2) ? Wv : Wp;
    unsigned short* out = wt + (size_t)z * 262144;
    const int row = tid >> 2, c0 = (tid & 3) * 16;
    const int kb = kbq * 64, nb = nbq * 64;
#pragma unroll
    for (int j = 0; j < 4; ++j) {
      float4 ld = *(const float4*)(W + (size_t)(kb + row) * DM + nb + c0 + j * 4);
      tile[row][c0 + j * 4 + 0] = ld.x;
      tile[row][c0 + j * 4 + 1] = ld.y;
      tile[row][c0 + j * 4 + 2] = ld.z;
      tile[row][c0 + j * 4 + 3] = ld.w;
    }
    __syncthreads();
    unsigned short ob[16];
#pragma unroll
    for (int j = 0; j < 16; ++j) ob[j] = f2bf(tile[c0 + j][row]);
    unsigned short* orow = out + (size_t)(nb + row) * DM + kb + c0;
    *(ushort8*)(orow) = *(ushort8*)&ob[0];
    *(ushort8*)(orow + 8) = *(ushort8*)&ob[8];
  } else {
    const int i = (bid - 2816) * 256 + tid;
    ushort8 vh, vl;
#pragma unroll
    for (int j = 0; j < 8; ++j) {
      float f = Wo[(size_t)i * 8 + j];
      unsigned short h = f2bf(f);
      vh[j] = h;
      vl[j] = f2bf(f - bf2f(h));
    }
    *(ushort8*)(woh + (size_t)i * 8) = vh;
    *(ushort8*)(wol + (size_t)i * 8) = vl;
  }
}

// ---------------------------------------------------------------------------
// v_ [B*KLEN][512] bf16 -> vt [b][n][d][KLEN] bf16 (global V transpose)
// ---------------------------------------------------------------------------
__global__ __launch_bounds__(256) void k_vtrans(
    const unsigned short* __restrict__ v_, unsigned short* __restrict__ vt) {
  __shared__ unsigned short tile[64][72];
  const int tid = threadIdx.x;
  const int row = tid >> 2, c0 = (tid & 3) * 16;
  const int kt = blockIdx.x;
  const int bn = blockIdx.y;
  const int bb = bn >> 3, n = bn & 7;
  const unsigned short* src =
      v_ + ((size_t)(bb * KLEN) + kt * 64 + row) * DM + n * DHEAD + c0;
  *(ushort8*)&tile[row][c0] = *(const ushort8*)src;
  *(ushort8*)&tile[row][c0 + 8] = *(const ushort8*)(src + 8);
  __syncthreads();
  unsigned short ob[16];
#pragma unroll
  for (int j = 0; j < 16; ++j) ob[j] = tile[c0 + j][row];
  unsigned short* dst =
      vt + ((size_t)bn * DHEAD + row) * KLEN + kt * 64 + c0;
  *(ushort8*)dst = *(ushort8*)&ob[0];
  *(ushort8*)(dst + 8) = *(ushort8*)&ob[8];
}

// ---------------------------------------------------------------------------
// Fused bf16 MFMA projection GEMM: C[M][512] = A[M][512] * Wt[512][512]^T
// ---------------------------------------------------------------------------
__global__ __launch_bounds__(256) void k_proj_mfma(
    const unsigned short* __restrict__ xb, const unsigned short* __restrict__ pb,
    const unsigned short* __restrict__ wt,
    unsigned short* __restrict__ q_, unsigned short* __restrict__ k_,
    unsigned short* __restrict__ v_, unsigned short* __restrict__ r_) {
  __shared__ unsigned short Abuf[128 * 64];
  __shared__ unsigned short Bbuf[128 * 64];
  const int tid = threadIdx.x, w = tid >> 6, lane = tid & 63;
  const int c = lane & 15, g = lane >> 4;
  const int wr = w >> 1, wc = w & 1;
  const int mb = blockIdx.x, nb = blockIdx.y;
  int prob, mloc;
  const unsigned short* A;
  unsigned short* C;
  if (mb < 32)        { prob = 0; mloc = mb;       A = xb; C = q_; }
  else if (mb < 96)   { prob = 1; mloc = mb - 32;  A = xb; C = k_; }
  else if (mb < 160)  { prob = 2; mloc = mb - 96;  A = xb; C = v_; }
  else                { prob = 3; mloc = mb - 160; A = pb; C = r_; }
  const unsigned short* W = wt + (size_t)prob * 262144;
  const int m0 = mloc * 128;
  const int lrow = lane >> 3, lslot = lane & 7;

  floatx4 acc[4][4];
#pragma unroll
  for (int m = 0; m < 4; ++m)
#pragma unroll
    for (int nn = 0; nn < 4; ++nn) acc[m][nn] = (floatx4){0.f, 0.f, 0.f, 0.f};

  for (int k0 = 0; k0 < DM; k0 += 64) {
    __syncthreads();
#pragma unroll
    for (int iq = 0; iq < 4; ++iq) {
      const int r0 = w * 32 + iq * 8;
      const int arow = r0 + lrow;
      const int mrow = m0 + arow;
      const int grow =
          (prob == 0) ? ((mrow >> 10) * KLEN + (mrow & 1023) + MLEN) : mrow;
      const int sgA = lslot ^ (arow & 7);
      GLOAD_LDS16(A + (size_t)grow * DM + k0 + sgA * 8, Abuf + r0 * 64);
      const int nrow = nb * 128 + arow;
      GLOAD_LDS16(W + (size_t)nrow * DM + k0 + sgA * 8, Bbuf + r0 * 64);
    }
    __syncthreads();
#pragma unroll
    for (int kk = 0; kk < 2; ++kk) {
      short8 af[4], bf[4];
#pragma unroll
      for (int m = 0; m < 4; ++m) {
        const int arow = wr * 64 + m * 16 + c;
        const int slot = (kk * 4 + g) ^ (arow & 7);
        af[m] = *(const short8*)(Abuf + arow * 64 + slot * 8);
      }
#pragma unroll
      for (int nn = 0; nn < 4; ++nn) {
        const int brow = wc * 64 + nn * 16 + c;
        const int slot = (kk * 4 + g) ^ (brow & 7);
        bf[nn] = *(const short8*)(Bbuf + brow * 64 + slot * 8);
      }
#pragma unroll
      for (int m = 0; m < 4; ++m)
#pragma unroll
        for (int nn = 0; nn < 4; ++nn)
          acc[m][nn] = __builtin_amdgcn_mfma_f32_16x16x32_bf16(
              af[m], bf[nn], acc[m][nn], 0, 0, 0);
    }
  }
#pragma unroll
  for (int m = 0; m < 4; ++m)
#pragma unroll
    for (int nn = 0; nn < 4; ++nn)
#pragma unroll
      for (int rg = 0; rg < 4; ++rg) {
        const int row = m0 + wr * 64 + m * 16 + 4 * g + rg;
        const int col = nb * 128 + wc * 64 + nn * 16 + c;
        C[(size_t)row * DM + col] = f2bf(acc[m][nn][rg]);
      }
}

// ---------------------------------------------------------------------------
// out[4096][512] = Ah*Bh^T + Al*Bh^T + Ah*Bl^T   (split-bf16, f32 accum)
// 64x64 tiles (R13 config — measured best).
// ---------------------------------------------------------------------------
__global__ __launch_bounds__(256) void k_out_mfma(
    const unsigned short* __restrict__ Ah, const unsigned short* __restrict__ Al,
    const unsigned short* __restrict__ Bh, const unsigned short* __restrict__ Bl,
    float* __restrict__ C) {
  __shared__ unsigned short bufAh[64 * 64], bufAl[64 * 64];
  __shared__ unsigned short bufBh[64 * 64], bufBl[64 * 64];
  const int tid = threadIdx.x, w = tid >> 6, lane = tid & 63;
  const int c = lane & 15, g = lane >> 4;
  const int wr = w >> 1, wc = w & 1;
  const int bm = blockIdx.x, bn = blockIdx.y;
  const int lrow = lane >> 3, lslot = lane & 7;
  floatx4 acc[2][2];
#pragma unroll
  for (int mi = 0; mi < 2; ++mi)
#pragma unroll
    for (int ni = 0; ni < 2; ++ni) acc[mi][ni] = (floatx4){0.f, 0.f, 0.f, 0.f};

  for (int k0 = 0; k0 < DM; k0 += 64) {
    __syncthreads();
#pragma unroll
    for (int iq = 0; iq < 2; ++iq) {
      const int r0 = w * 16 + iq * 8;
      const int arow = r0 + lrow;
      const int sg = lslot ^ (arow & 7);
      GLOAD_LDS16(Ah + (size_t)(bm * 64 + arow) * DM + k0 + sg * 8, bufAh + r0 * 64);
      GLOAD_LDS16(Al + (size_t)(bm * 64 + arow) * DM + k0 + sg * 8, bufAl + r0 * 64);
      GLOAD_LDS16(Bh + (size_t)(bn * 64 + arow) * DM + k0 + sg * 8, bufBh + r0 * 64);
      GLOAD_LDS16(Bl + (size_t)(bn * 64 + arow) * DM + k0 + sg * 8, bufBl + r0 * 64);
    }
    __syncthreads();
#pragma unroll
    for (int kk = 0; kk < 2; ++kk) {
      short8 ah[2], al[2], bh[2], bl[2];
#pragma unroll
      for (int mi = 0; mi < 2; ++mi) {
        const int row = wr * 32 + mi * 16 + c;
        const int slot = (kk * 4 + g) ^ (row & 7);
        ah[mi] = *(const short8*)(bufAh + row * 64 + slot * 8);
        al[mi] = *(const short8*)(bufAl + row * 64 + slot * 8);
      }
#pragma unroll
      for (int ni = 0; ni < 2; ++ni) {
        const int row = wc * 32 + ni * 16 + c;
        const int slot = (kk * 4 + g) ^ (row & 7);
        bh[ni] = *(const short8*)(bufBh + row * 64 + slot * 8);
        bl[ni] = *(const short8*)(bufBl + row * 64 + slot * 8);
      }
#pragma unroll
      for (int mi = 0; mi < 2; ++mi)
#pragma unroll
        for (int ni = 0; ni < 2; ++ni) {
          acc[mi][ni] = __builtin_amdgcn_mfma_f32_16x16x32_bf16(
              ah[mi], bh[ni], acc[mi][ni], 0, 0, 0);
          acc[mi][ni] = __builtin_amdgcn_mfma_f32_16x16x32_bf16(
              al[mi], bh[ni], acc[mi][ni], 0, 0, 0);
          acc[mi][ni] = __builtin_amdgcn_mfma_f32_16x16x32_bf16(
              ah[mi], bl[ni], acc[mi][ni], 0, 0, 0);
        }
    }
  }
#pragma unroll
  for (int mi = 0; mi < 2; ++mi)
#pragma unroll
    for (int ni = 0; ni < 2; ++ni)
#pragma unroll
      for (int rg = 0; rg < 4; ++rg) {
        const int row = bm * 64 + wr * 32 + mi * 16 + 4 * g + rg;
        const int col = bn * 64 + wc * 32 + ni * 16 + c;
        C[(size_t)row * DM + col] = acc[mi][ni][rg];
      }
}

// ---------------------------------------------------------------------------
// Flash MFMA attention, split-K: 512 thr = 8 waves = 4 q-subs x 2 key-halves.
// KVBLK=32; per-half K/V double-buffers + 128-row R ring; in-LDS merge.
// exp2-domain softmax, lane-local defer check (rowmax only on rescale),
// v_cvt_pk_bf16_f32 for P conversion.
// ---------------------------------------------------------------------------
__global__ __launch_bounds__(512, 4) void k_attn_mfma(
    const unsigned short* __restrict__ q, const unsigned short* __restrict__ k,
    const unsigned short* __restrict__ vt, const unsigned short* __restrict__ r,
    const float* __restrict__ bk, const float* __restrict__ br,
    unsigned short* __restrict__ aoh, unsigned short* __restrict__ aol) {
  __shared__ alignas(16) char SMEM[75776];
  unsigned short* Kt  = (unsigned short*)SMEM;            // [2h][2buf][32*64]
  unsigned short* VTt = (unsigned short*)(SMEM + 16384);  // [2h][2buf][64*32]
  unsigned short* Rr  = (unsigned short*)(SMEM + 32768);  // [2h][128*64]
  unsigned short* P   = (unsigned short*)(SMEM + 65536);  // [8][16][40]
  float* oC  = (float*)SMEM;                              // merge: [4][16][68]
  float* mlC = (float*)(SMEM + 17408);                    // merge: [4][2][16]

  const int tid = threadIdx.x;
  const int wave = tid >> 6;
  const int h = wave >> 2;         // key half
  const int w = wave & 3;          // q sub-wave
  const int lane = tid & 63;
  const int c = lane & 15;
  const int g = lane >> 4;
  const int n = blockIdx.y;
  const int b = blockIdx.z;
  const int grp = (n + NHEAD * b) >> 4;
  const int i0 = (grp ? (15 - (int)blockIdx.x) : (int)blockIdx.x) * 64;
  const int qb = i0 + w * 16;

  const unsigned short* vtbn = vt + (size_t)(b * NHEAD + n) * DHEAD * KLEN;
  const unsigned short* kbase = k + (size_t)(b * KLEN) * DM + n * DHEAD;
  const unsigned short* rbase_p = r + n * DHEAD;

  const int nkb = i0 / 32 + 34;
  const int nIt = nkb >> 1;
  const int g0r = 960 - i0;

  // Q fragments; scale = (1/8) * log2(e) -> softmax in exp2 domain
  const float QSC = 0.18033688011112042f;
  short8 aqk[2], aqr[2];
  {
    const unsigned short* qrow =
        q + ((size_t)(b * QLEN) + qb + c) * DM + n * DHEAD;
#pragma unroll
    for (int kb2 = 0; kb2 < 2; ++kb2) {
      short8 qv = *(const short8*)(qrow + kb2 * 32 + g * 8);
#pragma unroll
      for (int j = 0; j < 8; ++j) {
        int d = kb2 * 32 + g * 8 + j;
        float f = bf2f((unsigned short)qv[j]);
        aqk[kb2][j] = (short)f2bf((f + bk[n * DHEAD + d]) * QSC);
        aqr[kb2][j] = (short)f2bf((f + br[n * DHEAD + d]) * QSC);
      }
    }
  }

  floatx4 o[4];
#pragma unroll
  for (int t = 0; t < 4; ++t) o[t] = (floatx4){0.f, 0.f, 0.f, 0.f};
  float m[4], lsum[4], shc[4];
#pragma unroll
  for (int rg = 0; rg < 4; ++rg) { m[rg] = -1e30f; lsum[rg] = 0.f; shc[rg] = 0.f; }

  int bt = 0;

  auto STAGE = [&](int itn) {
    const int buf = itn & 1;
    const int hh = tid >> 8;
    const int idx = tid & 255;
    const int tn = hh * nIt + itn;
    {  // K [32key][64d], 8 slots/row
      const int row = idx >> 3, slot = idx & 7;
      GLOAD_LDS16(kbase + (size_t)(32 * tn + row) * DM + (slot ^ (row & 7)) * 8,
                  Kt + (hh * 2 + buf) * 2048 + idx * 8);
    }
    {  // V^T [64d][32key], 4 slots/row
      const int row = idx >> 2, slot = idx & 3;
      GLOAD_LDS16(vtbn + (size_t)row * KLEN + 32 * tn +
                      ((slot ^ ((row >> 1) & 3)) * 8),
                  VTt + (hh * 2 + buf) * 2048 + idx * 8);
    }
    {  // R: 32 new ring rows
      const int row = idx >> 3, slot = idx & 7;
      const int sb = (bt + 96) & 127;
      const int gst = g0r + hh * (32 * nIt);
      const int grow = min(gst + 32 * itn + 64 + row, KLEN - 1);
      GLOAD_LDS16(rbase_p + (size_t)grow * DM + (slot ^ (row & 7)) * 8,
                  Rr + hh * 8192 + (sb + row) * 64 + slot * 8);
    }
  };

  // prologue
  {
    const int hh = tid >> 8;
    const int idx = tid & 255;
    const int tn = hh * nIt;
    {
      const int row = idx >> 3, slot = idx & 7;
      GLOAD_LDS16(kbase + (size_t)(32 * tn + row) * DM + (slot ^ (row & 7)) * 8,
                  Kt + (hh * 2) * 2048 + idx * 8);
    }
    {
      const int row = idx >> 2, slot = idx & 3;
      GLOAD_LDS16(vtbn + (size_t)row * KLEN + 32 * tn +
                      ((slot ^ ((row >> 1) & 3)) * 8),
                  VTt + (hh * 2) * 2048 + idx * 8);
    }
  }
#pragma unroll
  for (int p = 0; p < 3; ++p) {
    const int Lr = tid + p * 512;
    const int hh = (Lr >= 768) ? 1 : 0;
    const int idx = Lr - hh * 768;
    const int row = idx >> 3, slot = idx & 7;
    const int gst = g0r + hh * (32 * nIt);
    const int grow = min(gst + row, KLEN - 1);
    GLOAD_LDS16(rbase_p + (size_t)grow * DM + (slot ^ (row & 7)) * 8,
                Rr + hh * 8192 + row * 64 + slot * 8);
  }
  __syncthreads();

  const int s0 = (g ^ (c & 7)) * 8;
  const int s1 = ((4 + g) ^ (c & 7)) * 8;
  const int vs0 = (g ^ ((c >> 1) & 3)) * 8;
  unsigned short* Pw = P + (size_t)wave * 640;

  for (int it = 0; it < nIt; ++it) {
    if (it + 1 < nIt) STAGE(it + 1);
    const int t = h * nIt + it;
    const bool act = (32 * t <= qb + 15 + MLEN);
    if (act) {
      const unsigned short* Kc = Kt + (h * 2 + (it & 1)) * 2048;
      const unsigned short* Vc = VTt + (h * 2 + (it & 1)) * 2048;
      const unsigned short* Rh = Rr + h * 8192;

      float sh[3][4];
      if (it == 0) {
        const int rs = ((bt + 16 * (3 - w)) & 127) + c;
        const unsigned short* Rrow = Rh + rs * 64;
        short8 rf0 = *(const short8*)(Rrow + s0);
        short8 rf1 = *(const short8*)(Rrow + s1);
        floatx4 bd = (floatx4){0.f, 0.f, 0.f, 0.f};
        bd = __builtin_amdgcn_mfma_f32_16x16x32_bf16(aqr[0], rf0, bd, 0, 0, 0);
        bd = __builtin_amdgcn_mfma_f32_16x16x32_bf16(aqr[1], rf1, bd, 0, 0, 0);
#pragma unroll
        for (int rg = 0; rg < 4; ++rg) {
          const int srcl = (g << 4) | ((15 + c - 4 * g - rg) & 15);
          sh[0][rg] = __shfl(bd[rg], srcl, 64);
        }
      } else {
#pragma unroll
        for (int rg = 0; rg < 4; ++rg) sh[0][rg] = shc[rg];
      }
#pragma unroll
      for (int t5 = 1; t5 < 3; ++t5) {
        const int rs = ((bt + 16 * (t5 + 3 - w)) & 127) + c;
        const unsigned short* Rrow = Rh + rs * 64;
        short8 rf0 = *(const short8*)(Rrow + s0);
        short8 rf1 = *(const short8*)(Rrow + s1);
        floatx4 bd = (floatx4){0.f, 0.f, 0.f, 0.f};
        bd = __builtin_amdgcn_mfma_f32_16x16x32_bf16(aqr[0], rf0, bd, 0, 0, 0);
        bd = __builtin_amdgcn_mfma_f32_16x16x32_bf16(aqr[1], rf1, bd, 0, 0, 0);
#pragma unroll
        for (int rg = 0; rg < 4; ++rg) {
          const int srcl = (g << 4) | ((15 + c - 4 * g - rg) & 15);
          sh[t5][rg] = __shfl(bd[rg], srcl, 64);
        }
      }
#pragma unroll
      for (int rg = 0; rg < 4; ++rg) shc[rg] = sh[2][rg];

      const int thr = qb + MLEN - 32 * t;
      floatx4 s[2];
      __builtin_amdgcn_s_setprio(1);
      if (thr >= 31) {
#pragma unroll
        for (int tau = 0; tau < 2; ++tau) {
          const int kr = tau * 16 + c;
          short8 kf0 = *(const short8*)(Kc + kr * 64 + s0);
          short8 kf1 = *(const short8*)(Kc + kr * 64 + s1);
          floatx4 acc = (floatx4){0.f, 0.f, 0.f, 0.f};
          acc = __builtin_amdgcn_mfma_f32_16x16x32_bf16(aqk[0], kf0, acc, 0, 0, 0);
          acc = __builtin_amdgcn_mfma_f32_16x16x32_bf16(aqk[1], kf1, acc, 0, 0, 0);
#pragma unroll
          for (int rg = 0; rg < 4; ++rg) {
            const int ql = 4 * g + rg;
            s[tau][rg] = acc[rg] + ((c > ql) ? sh[tau + 1][rg] : sh[tau][rg]);
          }
        }
      } else {
#pragma unroll
        for (int tau = 0; tau < 2; ++tau) {
          const int kr = tau * 16 + c;
          short8 kf0 = *(const short8*)(Kc + kr * 64 + s0);
          short8 kf1 = *(const short8*)(Kc + kr * 64 + s1);
          floatx4 acc = (floatx4){0.f, 0.f, 0.f, 0.f};
          acc = __builtin_amdgcn_mfma_f32_16x16x32_bf16(aqk[0], kf0, acc, 0, 0, 0);
          acc = __builtin_amdgcn_mfma_f32_16x16x32_bf16(aqk[1], kf1, acc, 0, 0, 0);
#pragma unroll
          for (int rg = 0; rg < 4; ++rg) {
            const int ql = 4 * g + rg;
            float sv = acc[rg] + ((c > ql) ? sh[tau + 1][rg] : sh[tau][rg]);
            if (tau * 16 + c > thr + ql) sv = -1e30f;
            s[tau][rg] = sv;
          }
        }
      }
      __builtin_amdgcn_s_setprio(0);

      // online softmax (exp2 domain): lane-local defer check; rowmax only in
      // the rare rescale branch (equivalent since m[] is row-uniform and
      // __all covers every (q,key) of the tile).
      float v2r[4];
      bool ok = true;
#pragma unroll
      for (int rg = 0; rg < 4; ++rg) {
        v2r[rg] = fmaxf(s[0][rg], s[1][rg]);
        ok = ok && (v2r[rg] <= m[rg] + 11.54f);
      }
      if (!__all(ok)) {
#pragma unroll
        for (int rg = 0; rg < 4; ++rg) {
          float mx = rowmax16(v2r[rg]);
          float mn = fmaxf(m[rg], mx);
          float fac = EXP2F(m[rg] - mn);
          m[rg] = mn;
          lsum[rg] *= fac;
#pragma unroll
          for (int td = 0; td < 4; ++td) o[td][rg] *= fac;
        }
      }
#pragma unroll
      for (int rg = 0; rg < 4; ++rg) {
        float p0 = EXP2F(s[0][rg] - m[rg]);
        float p1 = EXP2F(s[1][rg] - m[rg]);
        lsum[rg] += p0 + p1;
        unsigned int pk;
        asm("v_cvt_pk_bf16_f32 %0, %1, %2" : "=v"(pk) : "v"(p0), "v"(p1));
        Pw[(4 * g + rg) * 40 + c] = (unsigned short)pk;
        Pw[(4 * g + rg) * 40 + 16 + c] = (unsigned short)(pk >> 16);
      }

      short8 pa = *(const short8*)(Pw + c * 40 + g * 8);
      __builtin_amdgcn_s_setprio(1);
#pragma unroll
      for (int td = 0; td < 4; ++td) {
        short8 vb = *(const short8*)(Vc + (td * 16 + c) * 32 + vs0);
        o[td] = __builtin_amdgcn_mfma_f32_16x16x32_bf16(pa, vb, o[td], 0, 0, 0);
      }
      __builtin_amdgcn_s_setprio(0);
    }
    __syncthreads();
    bt = (bt + 32) & 127;
  }

#pragma unroll
  for (int rg = 0; rg < 4; ++rg) {
    float L = lsum[rg];
#pragma unroll
    for (int shm = 1; shm < 16; shm <<= 1) L += __shfl_xor(L, shm, 64);
    lsum[rg] = L;
  }

  if (h == 1) {
#pragma unroll
    for (int rg = 0; rg < 4; ++rg) {
      const int ql = 4 * g + rg;
#pragma unroll
      for (int td = 0; td < 4; ++td)
        oC[(w * 16 + ql) * 68 + td * 16 + c] = o[td][rg];
      if (c == 0) {
        mlC[w * 32 + ql] = m[rg];
        mlC[w * 32 + 16 + ql] = lsum[rg];
      }
    }
  }
  __syncthreads();
  if (h == 0) {
#pragma unroll
    for (int rg = 0; rg < 4; ++rg) {
      const int ql = 4 * g + rg;
      const float m1 = mlC[w * 32 + ql];
      const float l1 = mlC[w * 32 + 16 + ql];
      const float M = fmaxf(m[rg], m1);
      const float w0 = EXP2F(m[rg] - M);
      const float w1 = EXP2F(m1 - M);
      const float invl = 1.0f / (lsum[rg] * w0 + l1 * w1);
#pragma unroll
      for (int td = 0; td < 4; ++td) {
        float val = (o[td][rg] * w0 + oC[(w * 16 + ql) * 68 + td * 16 + c] * w1) * invl;
        unsigned short hi = f2bf(val);
        float lo = val - bf2f(hi);
        size_t off = ((size_t)(b * QLEN) + qb + ql) * DM + n * DHEAD + td * 16 + c;
        aoh[off] = hi;
        aol[off] = f2bf(lo);
      }
    }
  }
}

// ---------------------------------------------------------------------------
extern "C" void kernel_launch(void* const* d_in, const int* in_sizes, int n_in,
                              void* d_out, int out_size, void* d_ws, size_t ws_size,
                              hipStream_t stream) {
  const float* x  = (const float*)d_in[0];
  const float* p  = (const float*)d_in[1];
  const float* Wq = (const float*)d_in[2];
  const float* Wk = (const float*)d_in[3];
  const float* Wv = (const float*)d_in[4];
  const float* Wo = (const float*)d_in[5];
  const float* Wp = (const float*)d_in[6];
  const float* bk = (const float*)d_in[7];
  const float* br = (const float*)d_in[8];
  float* out = (float*)d_out;

  unsigned short* q_  = (unsigned short*)d_ws;        // 2M u16
  unsigned short* k_  = q_  + (size_t)2097152;        // 4M
  unsigned short* v_  = k_  + (size_t)4194304;        // 4M
  unsigned short* r_  = v_  + (size_t)4194304;        // 1M
  unsigned short* xb  = r_  + (size_t)1048576;        // 4M
  unsigned short* pb  = xb  + (size_t)4194304;        // 1M
  unsigned short* wt  = pb  + (size_t)1048576;        // 1M
  unsigned short* woh = wt  + (size_t)1048576;        // 256K
  unsigned short* wol = woh + (size_t)262144;         // 256K
  unsigned short* aoh = wol + (size_t)262144;         // 2M
  unsigned short* aol = aoh + (size_t)2097152;        // 2M
  unsigned short* vt_ = aol + (size_t)2097152;        // 4M

  k_prep<<<2944, 256, 0, stream>>>(x, p, Wq, Wk, Wv, Wp, Wo,
                                   xb, pb, wt, woh, wol);
  k_proj_mfma<<<dim3(176, 4), 256, 0, stream>>>(xb, pb, wt, q_, k_, v_, r_);
  k_vtrans<<<dim3(KLEN / 64, NHEAD * B_SZ), 256, 0, stream>>>(v_, vt_);
  k_attn_mfma<<<dim3(16, 8, 4), 512, 0, stream>>>(
      q_, k_, vt_, r_, bk, br, aoh, aol);
  k_out_mfma<<<dim3(64, 8), 256, 0, stream>>>(aoh, aol, woh, wol, out);
}

// Round 18
// 100.113 us; speedup vs baseline: 1.1415x; 1.0107x over previous
//
#include <hip/hip_runtime.h>
#include <hip/hip_bf16.h>
#include <stddef.h>
#include <stdint.h>

#define DM    512
#define NHEAD 8
#define DHEAD 64
#define QLEN  1024
#define KLEN  2048
#define MLEN  1024
#define B_SZ  4

typedef __attribute__((ext_vector_type(8))) short short8;
typedef __attribute__((ext_vector_type(8))) unsigned short ushort8;
typedef __attribute__((ext_vector_type(4))) float floatx4;

static __device__ __forceinline__ unsigned short f2bf(float f) {
  unsigned int u = __float_as_uint(f);
  unsigned int r = (u + 0x7FFFu + ((u >> 16) & 1u)) >> 16;
  return (unsigned short)r;
}
static __device__ __forceinline__ float bf2f(unsigned short h) {
  return __uint_as_float(((unsigned int)h) << 16);
}

template <int CTRL>
static __device__ __forceinline__ float maxdpp(float v) {
  int sh = __builtin_amdgcn_update_dpp(0, __float_as_int(v), CTRL, 0xF, 0xF, true);
  return fmaxf(v, __int_as_float(sh));
}
static __device__ __forceinline__ float rowmax16(float v) {
  v = maxdpp<0xB1>(v);    // quad_perm [1,0,3,2]
  v = maxdpp<0x4E>(v);    // quad_perm [2,3,0,1]
  v = maxdpp<0x124>(v);   // row_ror:4
  v = maxdpp<0x128>(v);   // row_ror:8
  return v;
}

#define EXP2F(x) __builtin_amdgcn_exp2f(x)

#define GLOAD_LDS16(gsrc, ldst)                                               \
  __builtin_amdgcn_global_load_lds(                                           \
      (const __attribute__((address_space(1))) unsigned int*)(gsrc),          \
      (__attribute__((address_space(3))) unsigned int*)(ldst), 16, 0, 0)

// ---------------------------------------------------------------------------
// Merged prep: x->bf16 | p->bf16 | Wq/k/v/p transpose | Wo hi/lo split.
// ---------------------------------------------------------------------------
__global__ __launch_bounds__(256) void k_prep(
    const float* __restrict__ x, const float* __restrict__ p,
    const float* __restrict__ Wq, const float* __restrict__ Wk,
    const float* __restrict__ Wv, const float* __restrict__ Wp,
    const float* __restrict__ Wo,
    unsigned short* __restrict__ xb, unsigned short* __restrict__ pb,
    unsigned short* __restrict__ wt,
    unsigned short* __restrict__ woh, unsigned short* __restrict__ wol) {
  __shared__ float tile[64][65];
  const int bid = blockIdx.x;
  const int tid = threadIdx.x;
  if (bid < 2048) {
    const int i = bid * 256 + tid;
    float4 a = *(const float4*)(x + (size_t)i * 8);
    float4 b = *(const float4*)(x + (size_t)i * 8 + 4);
    ushort8 o;
    o[0] = f2bf(a.x); o[1] = f2bf(a.y); o[2] = f2bf(a.z); o[3] = f2bf(a.w);
    o[4] = f2bf(b.x); o[5] = f2bf(b.y); o[6] = f2bf(b.z); o[7] = f2bf(b.w);
    *(ushort8*)(xb + (size_t)i * 8) = o;
  } else if (bid < 2560) {
    const int i = (bid - 2048) * 256 + tid;
    float4 a = *(const float4*)(p + (size_t)i * 8);
    float4 b = *(const float4*)(p + (size_t)i * 8 + 4);
    ushort8 o;
    o[0] = f2bf(a.x); o[1] = f2bf(a.y); o[2] = f2bf(a.z); o[3] = f2bf(a.w);
    o[4] = f2bf(b.x); o[5] = f2bf(b.y); o[6] = f2bf(b.z); o[7] = f2bf(b.w);
    *(ushort8*)(pb + (size_t)i * 8) = o;
  } else if (bid < 2816) {
    const int b2 = bid - 2560;
    const int nbq = b2 & 7, kbq = (b2 >> 3) & 7, z = b2 >> 6;
    const float* W = (z == 0) ? Wq : (z == 1) ? Wk : (z == 2) ? Wv : Wp;
    unsigned short* out = wt + (size_t)z * 262144;
    const int row = tid >> 2, c0 = (tid & 3) * 16;
    const int kb = kbq * 64, nb = nbq * 64;
#pragma unroll
    for (int j = 0; j < 4; ++j) {
      float4 ld = *(const float4*)(W + (size_t)(kb + row) * DM + nb + c0 + j * 4);
      tile[row][c0 + j * 4 + 0] = ld.x;
      tile[row][c0 + j * 4 + 1] = ld.y;
      tile[row][c0 + j * 4 + 2] = ld.z;
      tile[row][c0 + j * 4 + 3] = ld.w;
    }
    __syncthreads();
    unsigned short ob[16];
#pragma unroll
    for (int j = 0; j < 16; ++j) ob[j] = f2bf(tile[c0 + j][row]);
    unsigned short* orow = out + (size_t)(nb + row) * DM + kb + c0;
    *(ushort8*)(orow) = *(ushort8*)&ob[0];
    *(ushort8*)(orow + 8) = *(ushort8*)&ob[8];
  } else {
    const int i = (bid - 2816) * 256 + tid;
    ushort8 vh, vl;
#pragma unroll
    for (int j = 0; j < 8; ++j) {
      float f = Wo[(size_t)i * 8 + j];
      unsigned short h = f2bf(f);
      vh[j] = h;
      vl[j] = f2bf(f - bf2f(h));
    }
    *(ushort8*)(woh + (size_t)i * 8) = vh;
    *(ushort8*)(wol + (size_t)i * 8) = vl;
  }
}

// ---------------------------------------------------------------------------
// v_ [B*KLEN][512] bf16 -> vt [b][n][d][KLEN] bf16 (global V transpose)
// ---------------------------------------------------------------------------
__global__ __launch_bounds__(256) void k_vtrans(
    const unsigned short* __restrict__ v_, unsigned short* __restrict__ vt) {
  __shared__ unsigned short tile[64][72];
  const int tid = threadIdx.x;
  const int row = tid >> 2, c0 = (tid & 3) * 16;
  const int kt = blockIdx.x;
  const int bn = blockIdx.y;
  const int bb = bn >> 3, n = bn & 7;
  const unsigned short* src =
      v_ + ((size_t)(bb * KLEN) + kt * 64 + row) * DM + n * DHEAD + c0;
  *(ushort8*)&tile[row][c0] = *(const ushort8*)src;
  *(ushort8*)&tile[row][c0 + 8] = *(const ushort8*)(src + 8);
  __syncthreads();
  unsigned short ob[16];
#pragma unroll
  for (int j = 0; j < 16; ++j) ob[j] = tile[c0 + j][row];
  unsigned short* dst =
      vt + ((size_t)bn * DHEAD + row) * KLEN + kt * 64 + c0;
  *(ushort8*)dst = *(ushort8*)&ob[0];
  *(ushort8*)(dst + 8) = *(ushort8*)&ob[8];
}

// ---------------------------------------------------------------------------
// Fused bf16 MFMA projection GEMM: C[M][512] = A[M][512] * Wt[512][512]^T
// ---------------------------------------------------------------------------
__global__ __launch_bounds__(256) void k_proj_mfma(
    const unsigned short* __restrict__ xb, const unsigned short* __restrict__ pb,
    const unsigned short* __restrict__ wt,
    unsigned short* __restrict__ q_, unsigned short* __restrict__ k_,
    unsigned short* __restrict__ v_, unsigned short* __restrict__ r_) {
  __shared__ unsigned short Abuf[128 * 64];
  __shared__ unsigned short Bbuf[128 * 64];
  const int tid = threadIdx.x, w = tid >> 6, lane = tid & 63;
  const int c = lane & 15, g = lane >> 4;
  const int wr = w >> 1, wc = w & 1;
  const int mb = blockIdx.x, nb = blockIdx.y;
  int prob, mloc;
  const unsigned short* A;
  unsigned short* C;
  if (mb < 32)        { prob = 0; mloc = mb;       A = xb; C = q_; }
  else if (mb < 96)   { prob = 1; mloc = mb - 32;  A = xb; C = k_; }
  else if (mb < 160)  { prob = 2; mloc = mb - 96;  A = xb; C = v_; }
  else                { prob = 3; mloc = mb - 160; A = pb; C = r_; }
  const unsigned short* W = wt + (size_t)prob * 262144;
  const int m0 = mloc * 128;
  const int lrow = lane >> 3, lslot = lane & 7;

  floatx4 acc[4][4];
#pragma unroll
  for (int m = 0; m < 4; ++m)
#pragma unroll
    for (int nn = 0; nn < 4; ++nn) acc[m][nn] = (floatx4){0.f, 0.f, 0.f, 0.f};

  for (int k0 = 0; k0 < DM; k0 += 64) {
    __syncthreads();
#pragma unroll
    for (int iq = 0; iq < 4; ++iq) {
      const int r0 = w * 32 + iq * 8;
      const int arow = r0 + lrow;
      const int mrow = m0 + arow;
      const int grow =
          (prob == 0) ? ((mrow >> 10) * KLEN + (mrow & 1023) + MLEN) : mrow;
      const int sgA = lslot ^ (arow & 7);
      GLOAD_LDS16(A + (size_t)grow * DM + k0 + sgA * 8, Abuf + r0 * 64);
      const int nrow = nb * 128 + arow;
      GLOAD_LDS16(W + (size_t)nrow * DM + k0 + sgA * 8, Bbuf + r0 * 64);
    }
    __syncthreads();
#pragma unroll
    for (int kk = 0; kk < 2; ++kk) {
      short8 af[4], bf[4];
#pragma unroll
      for (int m = 0; m < 4; ++m) {
        const int arow = wr * 64 + m * 16 + c;
        const int slot = (kk * 4 + g) ^ (arow & 7);
        af[m] = *(const short8*)(Abuf + arow * 64 + slot * 8);
      }
#pragma unroll
      for (int nn = 0; nn < 4; ++nn) {
        const int brow = wc * 64 + nn * 16 + c;
        const int slot = (kk * 4 + g) ^ (brow & 7);
        bf[nn] = *(const short8*)(Bbuf + brow * 64 + slot * 8);
      }
#pragma unroll
      for (int m = 0; m < 4; ++m)
#pragma unroll
        for (int nn = 0; nn < 4; ++nn)
          acc[m][nn] = __builtin_amdgcn_mfma_f32_16x16x32_bf16(
              af[m], bf[nn], acc[m][nn], 0, 0, 0);
    }
  }
#pragma unroll
  for (int m = 0; m < 4; ++m)
#pragma unroll
    for (int nn = 0; nn < 4; ++nn)
#pragma unroll
      for (int rg = 0; rg < 4; ++rg) {
        const int row = m0 + wr * 64 + m * 16 + 4 * g + rg;
        const int col = nb * 128 + wc * 64 + nn * 16 + c;
        C[(size_t)row * DM + col] = f2bf(acc[m][nn][rg]);
      }
}

// ---------------------------------------------------------------------------
// out[4096][512] = Ah*Bh^T + Al*Bh^T + Ah*Bl^T   (split-bf16, f32 accum)
// 64x64 tiles (R13 config — measured best).
// ---------------------------------------------------------------------------
__global__ __launch_bounds__(256) void k_out_mfma(
    const unsigned short* __restrict__ Ah, const unsigned short* __restrict__ Al,
    const unsigned short* __restrict__ Bh, const unsigned short* __restrict__ Bl,
    float* __restrict__ C) {
  __shared__ unsigned short bufAh[64 * 64], bufAl[64 * 64];
  __shared__ unsigned short bufBh[64 * 64], bufBl[64 * 64];
  const int tid = threadIdx.x, w = tid >> 6, lane = tid & 63;
  const int c = lane & 15, g = lane >> 4;
  const int wr = w >> 1, wc = w & 1;
  const int bm = blockIdx.x, bn = blockIdx.y;
  const int lrow = lane >> 3, lslot = lane & 7;
  floatx4 acc[2][2];
#pragma unroll
  for (int mi = 0; mi < 2; ++mi)
#pragma unroll
    for (int ni = 0; ni < 2; ++ni) acc[mi][ni] = (floatx4){0.f, 0.f, 0.f, 0.f};

  for (int k0 = 0; k0 < DM; k0 += 64) {
    __syncthreads();
#pragma unroll
    for (int iq = 0; iq < 2; ++iq) {
      const int r0 = w * 16 + iq * 8;
      const int arow = r0 + lrow;
      const int sg = lslot ^ (arow & 7);
      GLOAD_LDS16(Ah + (size_t)(bm * 64 + arow) * DM + k0 + sg * 8, bufAh + r0 * 64);
      GLOAD_LDS16(Al + (size_t)(bm * 64 + arow) * DM + k0 + sg * 8, bufAl + r0 * 64);
      GLOAD_LDS16(Bh + (size_t)(bn * 64 + arow) * DM + k0 + sg * 8, bufBh + r0 * 64);
      GLOAD_LDS16(Bl + (size_t)(bn * 64 + arow) * DM + k0 + sg * 8, bufBl + r0 * 64);
    }
    __syncthreads();
#pragma unroll
    for (int kk = 0; kk < 2; ++kk) {
      short8 ah[2], al[2], bh[2], bl[2];
#pragma unroll
      for (int mi = 0; mi < 2; ++mi) {
        const int row = wr * 32 + mi * 16 + c;
        const int slot = (kk * 4 + g) ^ (row & 7);
        ah[mi] = *(const short8*)(bufAh + row * 64 + slot * 8);
        al[mi] = *(const short8*)(bufAl + row * 64 + slot * 8);
      }
#pragma unroll
      for (int ni = 0; ni < 2; ++ni) {
        const int row = wc * 32 + ni * 16 + c;
        const int slot = (kk * 4 + g) ^ (row & 7);
        bh[ni] = *(const short8*)(bufBh + row * 64 + slot * 8);
        bl[ni] = *(const short8*)(bufBl + row * 64 + slot * 8);
      }
#pragma unroll
      for (int mi = 0; mi < 2; ++mi)
#pragma unroll
        for (int ni = 0; ni < 2; ++ni) {
          acc[mi][ni] = __builtin_amdgcn_mfma_f32_16x16x32_bf16(
              ah[mi], bh[ni], acc[mi][ni], 0, 0, 0);
          acc[mi][ni] = __builtin_amdgcn_mfma_f32_16x16x32_bf16(
              al[mi], bh[ni], acc[mi][ni], 0, 0, 0);
          acc[mi][ni] = __builtin_amdgcn_mfma_f32_16x16x32_bf16(
              ah[mi], bl[ni], acc[mi][ni], 0, 0, 0);
        }
    }
  }
#pragma unroll
  for (int mi = 0; mi < 2; ++mi)
#pragma unroll
    for (int ni = 0; ni < 2; ++ni)
#pragma unroll
      for (int rg = 0; rg < 4; ++rg) {
        const int row = bm * 64 + wr * 32 + mi * 16 + 4 * g + rg;
        const int col = bn * 64 + wc * 32 + ni * 16 + c;
        C[(size_t)row * DM + col] = acc[mi][ni][rg];
      }
}

// ---------------------------------------------------------------------------
// Flash MFMA attention, split-K: 512 thr = 8 waves = 4 q-subs x 2 key-halves.
// KVBLK=32; per-half K/V double-buffers + 128-row R ring; in-LDS merge.
// exp2-domain softmax, lane-local defer check, cvt_pk P-stores issued early,
// setprio around all MFMA clusters (BD, AC, PV).
// ---------------------------------------------------------------------------
__global__ __launch_bounds__(512, 4) void k_attn_mfma(
    const unsigned short* __restrict__ q, const unsigned short* __restrict__ k,
    const unsigned short* __restrict__ vt, const unsigned short* __restrict__ r,
    const float* __restrict__ bk, const float* __restrict__ br,
    unsigned short* __restrict__ aoh, unsigned short* __restrict__ aol) {
  __shared__ alignas(16) char SMEM[75776];
  unsigned short* Kt  = (unsigned short*)SMEM;            // [2h][2buf][32*64]
  unsigned short* VTt = (unsigned short*)(SMEM + 16384);  // [2h][2buf][64*32]
  unsigned short* Rr  = (unsigned short*)(SMEM + 32768);  // [2h][128*64]
  unsigned short* P   = (unsigned short*)(SMEM + 65536);  // [8][16][40]
  float* oC  = (float*)SMEM;                              // merge: [4][16][68]
  float* mlC = (float*)(SMEM + 17408);                    // merge: [4][2][16]

  const int tid = threadIdx.x;
  const int wave = tid >> 6;
  const int h = wave >> 2;         // key half
  const int w = wave & 3;          // q sub-wave
  const int lane = tid & 63;
  const int c = lane & 15;
  const int g = lane >> 4;
  const int n = blockIdx.y;
  const int b = blockIdx.z;
  const int grp = (n + NHEAD * b) >> 4;
  const int i0 = (grp ? (15 - (int)blockIdx.x) : (int)blockIdx.x) * 64;
  const int qb = i0 + w * 16;

  const unsigned short* vtbn = vt + (size_t)(b * NHEAD + n) * DHEAD * KLEN;
  const unsigned short* kbase = k + (size_t)(b * KLEN) * DM + n * DHEAD;
  const unsigned short* rbase_p = r + n * DHEAD;

  const int nkb = i0 / 32 + 34;
  const int nIt = nkb >> 1;
  const int g0r = 960 - i0;

  // Q fragments; scale = (1/8) * log2(e) -> softmax in exp2 domain
  const float QSC = 0.18033688011112042f;
  short8 aqk[2], aqr[2];
  {
    const unsigned short* qrow =
        q + ((size_t)(b * QLEN) + qb + c) * DM + n * DHEAD;
#pragma unroll
    for (int kb2 = 0; kb2 < 2; ++kb2) {
      short8 qv = *(const short8*)(qrow + kb2 * 32 + g * 8);
#pragma unroll
      for (int j = 0; j < 8; ++j) {
        int d = kb2 * 32 + g * 8 + j;
        float f = bf2f((unsigned short)qv[j]);
        aqk[kb2][j] = (short)f2bf((f + bk[n * DHEAD + d]) * QSC);
        aqr[kb2][j] = (short)f2bf((f + br[n * DHEAD + d]) * QSC);
      }
    }
  }

  floatx4 o[4];
#pragma unroll
  for (int t = 0; t < 4; ++t) o[t] = (floatx4){0.f, 0.f, 0.f, 0.f};
  float m[4], lsum[4], shc[4];
#pragma unroll
  for (int rg = 0; rg < 4; ++rg) { m[rg] = -1e30f; lsum[rg] = 0.f; shc[rg] = 0.f; }

  int bt = 0;

  auto STAGE = [&](int itn) {
    const int buf = itn & 1;
    const int hh = tid >> 8;
    const int idx = tid & 255;
    const int tn = hh * nIt + itn;
    {  // K [32key][64d], 8 slots/row
      const int row = idx >> 3, slot = idx & 7;
      GLOAD_LDS16(kbase + (size_t)(32 * tn + row) * DM + (slot ^ (row & 7)) * 8,
                  Kt + (hh * 2 + buf) * 2048 + idx * 8);
    }
    {  // V^T [64d][32key], 4 slots/row
      const int row = idx >> 2, slot = idx & 3;
      GLOAD_LDS16(vtbn + (size_t)row * KLEN + 32 * tn +
                      ((slot ^ ((row >> 1) & 3)) * 8),
                  VTt + (hh * 2 + buf) * 2048 + idx * 8);
    }
    {  // R: 32 new ring rows
      const int row = idx >> 3, slot = idx & 7;
      const int sb = (bt + 96) & 127;
      const int gst = g0r + hh * (32 * nIt);
      const int grow = min(gst + 32 * itn + 64 + row, KLEN - 1);
      GLOAD_LDS16(rbase_p + (size_t)grow * DM + (slot ^ (row & 7)) * 8,
                  Rr + hh * 8192 + (sb + row) * 64 + slot * 8);
    }
  };

  // prologue
  {
    const int hh = tid >> 8;
    const int idx = tid & 255;
    const int tn = hh * nIt;
    {
      const int row = idx >> 3, slot = idx & 7;
      GLOAD_LDS16(kbase + (size_t)(32 * tn + row) * DM + (slot ^ (row & 7)) * 8,
                  Kt + (hh * 2) * 2048 + idx * 8);
    }
    {
      const int row = idx >> 2, slot = idx & 3;
      GLOAD_LDS16(vtbn + (size_t)row * KLEN + 32 * tn +
                      ((slot ^ ((row >> 1) & 3)) * 8),
                  VTt + (hh * 2) * 2048 + idx * 8);
    }
  }
#pragma unroll
  for (int p = 0; p < 3; ++p) {
    const int Lr = tid + p * 512;
    const int hh = (Lr >= 768) ? 1 : 0;
    const int idx = Lr - hh * 768;
    const int row = idx >> 3, slot = idx & 7;
    const int gst = g0r + hh * (32 * nIt);
    const int grow = min(gst + row, KLEN - 1);
    GLOAD_LDS16(rbase_p + (size_t)grow * DM + (slot ^ (row & 7)) * 8,
                Rr + hh * 8192 + row * 64 + slot * 8);
  }
  __syncthreads();

  const int s0 = (g ^ (c & 7)) * 8;
  const int s1 = ((4 + g) ^ (c & 7)) * 8;
  const int vs0 = (g ^ ((c >> 1) & 3)) * 8;
  unsigned short* Pw = P + (size_t)wave * 640;

  for (int it = 0; it < nIt; ++it) {
    if (it + 1 < nIt) STAGE(it + 1);
    const int t = h * nIt + it;
    const bool act = (32 * t <= qb + 15 + MLEN);
    if (act) {
      const unsigned short* Kc = Kt + (h * 2 + (it & 1)) * 2048;
      const unsigned short* Vc = VTt + (h * 2 + (it & 1)) * 2048;
      const unsigned short* Rh = Rr + h * 8192;

      float sh[3][4];
      __builtin_amdgcn_s_setprio(1);
      if (it == 0) {
        const int rs = ((bt + 16 * (3 - w)) & 127) + c;
        const unsigned short* Rrow = Rh + rs * 64;
        short8 rf0 = *(const short8*)(Rrow + s0);
        short8 rf1 = *(const short8*)(Rrow + s1);
        floatx4 bd = (floatx4){0.f, 0.f, 0.f, 0.f};
        bd = __builtin_amdgcn_mfma_f32_16x16x32_bf16(aqr[0], rf0, bd, 0, 0, 0);
        bd = __builtin_amdgcn_mfma_f32_16x16x32_bf16(aqr[1], rf1, bd, 0, 0, 0);
#pragma unroll
        for (int rg = 0; rg < 4; ++rg) {
          const int srcl = (g << 4) | ((15 + c - 4 * g - rg) & 15);
          sh[0][rg] = __shfl(bd[rg], srcl, 64);
        }
      } else {
#pragma unroll
        for (int rg = 0; rg < 4; ++rg) sh[0][rg] = shc[rg];
      }
#pragma unroll
      for (int t5 = 1; t5 < 3; ++t5) {
        const int rs = ((bt + 16 * (t5 + 3 - w)) & 127) + c;
        const unsigned short* Rrow = Rh + rs * 64;
        short8 rf0 = *(const short8*)(Rrow + s0);
        short8 rf1 = *(const short8*)(Rrow + s1);
        floatx4 bd = (floatx4){0.f, 0.f, 0.f, 0.f};
        bd = __builtin_amdgcn_mfma_f32_16x16x32_bf16(aqr[0], rf0, bd, 0, 0, 0);
        bd = __builtin_amdgcn_mfma_f32_16x16x32_bf16(aqr[1], rf1, bd, 0, 0, 0);
#pragma unroll
        for (int rg = 0; rg < 4; ++rg) {
          const int srcl = (g << 4) | ((15 + c - 4 * g - rg) & 15);
          sh[t5][rg] = __shfl(bd[rg], srcl, 64);
        }
      }
#pragma unroll
      for (int rg = 0; rg < 4; ++rg) shc[rg] = sh[2][rg];

      const int thr = qb + MLEN - 32 * t;
      floatx4 s[2];
      if (thr >= 31) {
#pragma unroll
        for (int tau = 0; tau < 2; ++tau) {
          const int kr = tau * 16 + c;
          short8 kf0 = *(const short8*)(Kc + kr * 64 + s0);
          short8 kf1 = *(const short8*)(Kc + kr * 64 + s1);
          floatx4 acc = (floatx4){0.f, 0.f, 0.f, 0.f};
          acc = __builtin_amdgcn_mfma_f32_16x16x32_bf16(aqk[0], kf0, acc, 0, 0, 0);
          acc = __builtin_amdgcn_mfma_f32_16x16x32_bf16(aqk[1], kf1, acc, 0, 0, 0);
#pragma unroll
          for (int rg = 0; rg < 4; ++rg) {
            const int ql = 4 * g + rg;
            s[tau][rg] = acc[rg] + ((c > ql) ? sh[tau + 1][rg] : sh[tau][rg]);
          }
        }
      } else {
#pragma unroll
        for (int tau = 0; tau < 2; ++tau) {
          const int kr = tau * 16 + c;
          short8 kf0 = *(const short8*)(Kc + kr * 64 + s0);
          short8 kf1 = *(const short8*)(Kc + kr * 64 + s1);
          floatx4 acc = (floatx4){0.f, 0.f, 0.f, 0.f};
          acc = __builtin_amdgcn_mfma_f32_16x16x32_bf16(aqk[0], kf0, acc, 0, 0, 0);
          acc = __builtin_amdgcn_mfma_f32_16x16x32_bf16(aqk[1], kf1, acc, 0, 0, 0);
#pragma unroll
          for (int rg = 0; rg < 4; ++rg) {
            const int ql = 4 * g + rg;
            float sv = acc[rg] + ((c > ql) ? sh[tau + 1][rg] : sh[tau][rg]);
            if (tau * 16 + c > thr + ql) sv = -1e30f;
            s[tau][rg] = sv;
          }
        }
      }
      __builtin_amdgcn_s_setprio(0);

      // online softmax (exp2 domain): lane-local defer check; rowmax only in
      // the rare rescale branch.
      float v2r[4];
      bool ok = true;
#pragma unroll
      for (int rg = 0; rg < 4; ++rg) {
        v2r[rg] = fmaxf(s[0][rg], s[1][rg]);
        ok = ok && (v2r[rg] <= m[rg] + 11.54f);
      }
      if (!__all(ok)) {
#pragma unroll
        for (int rg = 0; rg < 4; ++rg) {
          float mx = rowmax16(v2r[rg]);
          float mn = fmaxf(m[rg], mx);
          float fac = EXP2F(m[rg] - mn);
          m[rg] = mn;
          lsum[rg] *= fac;
#pragma unroll
          for (int td = 0; td < 4; ++td) o[td][rg] *= fac;
        }
      }
      // P stores first (overlap ds_write latency with the lsum adds)
      float p0v[4], p1v[4];
#pragma unroll
      for (int rg = 0; rg < 4; ++rg) {
        p0v[rg] = EXP2F(s[0][rg] - m[rg]);
        p1v[rg] = EXP2F(s[1][rg] - m[rg]);
        unsigned int pk;
        asm("v_cvt_pk_bf16_f32 %0, %1, %2" : "=v"(pk) : "v"(p0v[rg]), "v"(p1v[rg]));
        Pw[(4 * g + rg) * 40 + c] = (unsigned short)pk;
        Pw[(4 * g + rg) * 40 + 16 + c] = (unsigned short)(pk >> 16);
      }
#pragma unroll
      for (int rg = 0; rg < 4; ++rg) lsum[rg] += p0v[rg] + p1v[rg];

      short8 pa = *(const short8*)(Pw + c * 40 + g * 8);
      __builtin_amdgcn_s_setprio(1);
#pragma unroll
      for (int td = 0; td < 4; ++td) {
        short8 vb = *(const short8*)(Vc + (td * 16 + c) * 32 + vs0);
        o[td] = __builtin_amdgcn_mfma_f32_16x16x32_bf16(pa, vb, o[td], 0, 0, 0);
      }
      __builtin_amdgcn_s_setprio(0);
    }
    __syncthreads();
    bt = (bt + 32) & 127;
  }

#pragma unroll
  for (int rg = 0; rg < 4; ++rg) {
    float L = lsum[rg];
#pragma unroll
    for (int shm = 1; shm < 16; shm <<= 1) L += __shfl_xor(L, shm, 64);
    lsum[rg] = L;
  }

  if (h == 1) {
#pragma unroll
    for (int rg = 0; rg < 4; ++rg) {
      const int ql = 4 * g + rg;
#pragma unroll
      for (int td = 0; td < 4; ++td)
        oC[(w * 16 + ql) * 68 + td * 16 + c] = o[td][rg];
      if (c == 0) {
        mlC[w * 32 + ql] = m[rg];
        mlC[w * 32 + 16 + ql] = lsum[rg];
      }
    }
  }
  __syncthreads();
  if (h == 0) {
#pragma unroll
    for (int rg = 0; rg < 4; ++rg) {
      const int ql = 4 * g + rg;
      const float m1 = mlC[w * 32 + ql];
      const float l1 = mlC[w * 32 + 16 + ql];
      const float M = fmaxf(m[rg], m1);
      const float w0 = EXP2F(m[rg] - M);
      const float w1 = EXP2F(m1 - M);
      const float invl = 1.0f / (lsum[rg] * w0 + l1 * w1);
#pragma unroll
      for (int td = 0; td < 4; ++td) {
        float val = (o[td][rg] * w0 + oC[(w * 16 + ql) * 68 + td * 16 + c] * w1) * invl;
        unsigned short hi = f2bf(val);
        float lo = val - bf2f(hi);
        size_t off = ((size_t)(b * QLEN) + qb + ql) * DM + n * DHEAD + td * 16 + c;
        aoh[off] = hi;
        aol[off] = f2bf(lo);
      }
    }
  }
}

// ---------------------------------------------------------------------------
extern "C" void kernel_launch(void* const* d_in, const int* in_sizes, int n_in,
                              void* d_out, int out_size, void* d_ws, size_t ws_size,
                              hipStream_t stream) {
  const float* x  = (const float*)d_in[0];
  const float* p  = (const float*)d_in[1];
  const float* Wq = (const float*)d_in[2];
  const float* Wk = (const float*)d_in[3];
  const float* Wv = (const float*)d_in[4];
  const float* Wo = (const float*)d_in[5];
  const float* Wp = (const float*)d_in[6];
  const float* bk = (const float*)d_in[7];
  const float* br = (const float*)d_in[8];
  float* out = (float*)d_out;

  unsigned short* q_  = (unsigned short*)d_ws;        // 2M u16
  unsigned short* k_  = q_  + (size_t)2097152;        // 4M
  unsigned short* v_  = k_  + (size_t)4194304;        // 4M
  unsigned short* r_  = v_  + (size_t)4194304;        // 1M
  unsigned short* xb  = r_  + (size_t)1048576;        // 4M
  unsigned short* pb  = xb  + (size_t)4194304;        // 1M
  unsigned short* wt  = pb  + (size_t)1048576;        // 1M
  unsigned short* woh = wt  + (size_t)1048576;        // 256K
  unsigned short* wol = woh + (size_t)262144;         // 256K
  unsigned short* aoh = wol + (size_t)262144;         // 2M
  unsigned short* aol = aoh + (size_t)2097152;        // 2M
  unsigned short* vt_ = aol + (size_t)2097152;        // 4M

  k_prep<<<2944, 256, 0, stream>>>(x, p, Wq, Wk, Wv, Wp, Wo,
                                   xb, pb, wt, woh, wol);
  k_proj_mfma<<<dim3(176, 4), 256, 0, stream>>>(xb, pb, wt, q_, k_, v_, r_);
  k_vtrans<<<dim3(KLEN / 64, NHEAD * B_SZ), 256, 0, stream>>>(v_, vt_);
  k_attn_mfma<<<dim3(16, 8, 4), 512, 0, stream>>>(
      q_, k_, vt_, r_, bk, br, aoh, aol);
  k_out_mfma<<<dim3(64, 8), 256, 0, stream>>>(aoh, aol, woh, wol, out);
}